// Round 1
// baseline (3612.058 us; speedup 1.0000x reference)
//
#include <hip/hip_runtime.h>
#include <cstddef>
#include <cstdint>

#define WSLOPE 0.2f
#define WEPS 1e-12f

typedef __attribute__((ext_vector_type(8))) short bf16x8;
typedef __attribute__((ext_vector_type(4))) float f32x4;

__device__ __forceinline__ float waveSum(float v) {
#pragma unroll
    for (int off = 32; off > 0; off >>= 1) v += __shfl_xor(v, off, 64);
    return v;
}
__device__ __forceinline__ float eluf(float v) { return v > 0.f ? v : expm1f(v); }
__device__ __forceinline__ short f2bf(float f) {
    union { float f; uint32_t u; } v; v.f = f;
    uint32_t r = v.u + 0x7FFF + ((v.u >> 16) & 1);
    return (short)(r >> 16);
}

// ---------------- per-node inverse L2 norm of x ----------------
__global__ void k_invnorm(const float* __restrict__ x, float* __restrict__ invn, int N) {
    int wid = blockIdx.x * 4 + (threadIdx.x >> 6);
    int lane = threadIdx.x & 63;
    if (wid >= N) return;
    const float* p = x + (size_t)wid * 100;
    float a = p[lane];
    float ss = a * a;
    if (lane < 36) { float b = p[lane + 64]; ss += b * b; }
    ss = waveSum(ss);
    if (lane == 0) invn[wid] = 1.f / fmaxf(sqrtf(ss), WEPS);
}

// ---------------- generic CSR build (counting sort) ----------------
__global__ void k_count(const int* __restrict__ keys, int* __restrict__ cnt, int n) {
    int i = blockIdx.x * 256 + threadIdx.x;
    if (i < n) atomicAdd(&cnt[keys[i]], 1);
}

#define SCAN_CHUNK 2048
__global__ void k_blocksum(const int* __restrict__ cnt, int* __restrict__ bsum, int n) {
    __shared__ int sh[256];
    int b = blockIdx.x, t = threadIdx.x;
    int base = b * SCAN_CHUNK;
    int s = 0;
    for (int i = t; i < SCAN_CHUNK; i += 256) { int idx = base + i; if (idx < n) s += cnt[idx]; }
    sh[t] = s; __syncthreads();
    for (int off = 128; off > 0; off >>= 1) { if (t < off) sh[t] += sh[t + off]; __syncthreads(); }
    if (t == 0) bsum[b] = sh[0];
}

__global__ void k_scanwrite(const int* __restrict__ cnt, const int* __restrict__ bsum,
                            int* __restrict__ offs, int* __restrict__ cur, int n, int nb) {
    __shared__ int sh[256];
    __shared__ int sbase;
    int b = blockIdx.x, t = threadIdx.x;
    if (t == 0) { int s = 0; for (int i = 0; i < b; ++i) s += bsum[i]; sbase = s; }
    __syncthreads();
    int base = b * SCAN_CHUNK;
    int loc[8]; int ts = 0;
#pragma unroll
    for (int i = 0; i < 8; ++i) { int idx = base + t * 8 + i; int v = (idx < n) ? cnt[idx] : 0; loc[i] = ts; ts += v; }
    sh[t] = ts; __syncthreads();
    for (int off = 1; off < 256; off <<= 1) {
        int v = (t >= off) ? sh[t - off] : 0;
        __syncthreads();
        sh[t] += v;
        __syncthreads();
    }
    int excl = (t == 0) ? 0 : sh[t - 1];
    int gbase = sbase + excl;
#pragma unroll
    for (int i = 0; i < 8; ++i) {
        int idx = base + t * 8 + i;
        if (idx < n) { offs[idx] = gbase + loc[i]; cur[idx] = gbase + loc[i]; }
    }
    if (b == nb - 1 && t == 255) offs[n] = sbase + sh[255];
}

__global__ void k_scatter(const int* __restrict__ keys, int* __restrict__ cur, int* __restrict__ lists, int n) {
    int i = blockIdx.x * 256 + threadIdx.x;
    if (i < n) { int p = atomicAdd(&cur[keys[i]], 1); lists[p] = i; }
}

// ---------------- attention vector ----------------
__global__ void k_watt(const float* __restrict__ att, const float* __restrict__ W,
                       float* __restrict__ wa, int H, int DH, int K) {
    int id = blockIdx.x * 256 + threadIdx.x;
    if (id >= H * K) return;
    int h = id / K, k = id % K;
    float s = 0.f;
    for (int j = 0; j < DH; ++j) s += att[h * DH + j] * W[(size_t)(h * DH + j) * K + k];
    wa[id] = s;
}

// ---------------- per-node partial dots ----------------
template<bool HOP2>
__global__ void k_dots(const float* __restrict__ feat, const float* __restrict__ invn,
                       const float* __restrict__ wa, float* __restrict__ rdot,
                       float* __restrict__ cdot, int N) {
    int wid = blockIdx.x * 4 + (threadIdx.x >> 6);
    int lane = threadIdx.x & 63;
    if (wid >= N) return;
    if (!HOP2) {
        float inv = invn[wid];
        const float* p = feat + (size_t)wid * 100;
        float f0 = p[lane] * inv;
        float f1 = (lane < 36) ? p[lane + 64] * inv : 0.f;
#pragma unroll
        for (int h = 0; h < 2; ++h) {
            const float* w = wa + h * 300;
            float r = f0 * w[lane] + ((lane < 36) ? f1 * w[lane + 64] : 0.f);
            float c = f0 * w[100 + lane] + ((lane < 36) ? f1 * w[100 + lane + 64] : 0.f);
            r = waveSum(r); c = waveSum(c);
            if (lane == 0) { rdot[wid * 2 + h] = r; cdot[wid * 2 + h] = c; }
        }
    } else {
        const float* p = feat + (size_t)wid * 200;
        float r = 0.f, c = 0.f;
#pragma unroll
        for (int m = 0; m < 4; ++m) {
            int d = lane + m * 64;
            if (d < 200) { float f = p[d]; r += f * wa[d]; c += f * wa[200 + d]; }
        }
        r = waveSum(r); c = waveSum(c);
        if (lane == 0) { rdot[wid] = r; cdot[wid] = c; }
    }
}

// ---------------- per-type dot ----------------
__global__ void k_gdot(const float* __restrict__ gsrc, const float* __restrict__ wa,
                       float* __restrict__ gdot, int M, int H, int GL, int K) {
    int id = blockIdx.x * 256 + threadIdx.x;
    if (id >= M * H) return;
    int m = id / H, h = id % H;
    float s = 0.f;
    const float* w = wa + h * K + 2 * GL;
    const float* gm = gsrc + (size_t)m * GL;
    for (int kk = 0; kk < GL; ++kk) s += gm[kk] * w[kk];
    gdot[id] = s;
}

// ---------------- per-edge weight ----------------
__global__ void k_ew(const int* __restrict__ row, const int* __restrict__ col, const int* __restrict__ et,
                     const float* __restrict__ rdot, const float* __restrict__ cdot,
                     const float* __restrict__ gdot, float* __restrict__ ew, int E, int H) {
    int id = blockIdx.x * 256 + threadIdx.x;
    if (id >= E * H) return;
    int e = id / H, h = id - e * H;
    float a = rdot[row[e] * H + h] + cdot[col[e] * H + h] + gdot[et[e] * H + h];
    float lr = a > 0.f ? a : WSLOPE * a;
    ew[id] = expf(-lr);
}

// ---------------- CSR aggregation: wave per node ----------------
template<int H, bool HOP2>
__global__ void k_agg(const int* __restrict__ offs, const int* __restrict__ lists,
                      const int* __restrict__ nbrArr, const int* __restrict__ etype,
                      const float* __restrict__ ew, const float* __restrict__ projg,
                      const float* __restrict__ feat, const float* __restrict__ invn,
                      short* __restrict__ agg_b, float* __restrict__ hb, int n0, int n1) {
    int node = n0 + blockIdx.x * 4 + (threadIdx.x >> 6);
    int lane = threadIdx.x & 63;
    if (node >= n1) return;
    int o = offs[node];
    int deg = offs[node + 1] - o;
    float va[7];
#pragma unroll
    for (int m = 0; m < 7; ++m) va[m] = 0.f;
    if (deg > 0) {
        float s0 = 0.f, s1 = 0.f;
        for (int i = lane; i < deg; i += 64) {
            int e = lists[o + i];
            s0 += ew[e * H];
            if (H == 2) s1 += ew[e * H + 1];
        }
        s0 = waveSum(s0);
        float rd0 = 1.f / s0, rd1 = rd0;
        if (H == 2) { s1 = waveSum(s1); rd1 = 1.f / s1; }
        for (int j = 0; j < deg; ++j) {
            int e = lists[o + j];
            float a0 = ew[e * H] * rd0;
            float a1 = (H == 2) ? ew[e * H + 1] * rd1 : a0;
            int nbr = nbrArr[e];
            int et = etype[e];
            const float* pgr = projg + (size_t)et * 200;
            if (!HOP2) {
                float inv = invn[nbr];
                const float* fr = feat + (size_t)nbr * 100;
#pragma unroll
                for (int m = 0; m < 7; ++m) {
                    int d = lane + m * 64;
                    if (d < 200) {
                        int kk = d >= 100 ? d - 100 : d;
                        float al = d < 100 ? a0 : a1;
                        va[m] += al * fr[kk] * inv;
                    } else if (d < 400) {
                        int dd = d - 200;
                        float al = dd < 100 ? a0 : a1;
                        va[m] += al * pgr[dd];
                    }
                }
            } else {
                const float* fr = feat + (size_t)nbr * 200;
#pragma unroll
                for (int m = 0; m < 7; ++m) {
                    int d = lane + m * 64;
                    if (d < 200) va[m] += a0 * fr[d];
                    else if (d < 400) va[m] += a0 * pgr[d - 200];
                }
            }
        }
    }
    size_t rb = (size_t)(node - n0);
#pragma unroll
    for (int m = 0; m < 7; ++m) {
        int d = lane + m * 64;
        if (d < 200) {
            int slot = HOP2 ? d : (d < 100 ? d : d + 12);
            agg_b[rb * 224 + slot] = f2bf(va[m]);
        } else if (d < 400) {
            hb[rb * 200 + (d - 200)] = va[m];
        }
    }
    // zero the pad slots of this row
    if (!HOP2) {
        if (lane < 24) { int s = lane < 12 ? 100 + lane : 200 + lane; agg_b[rb * 224 + s] = 0; }
    } else {
        if (lane < 24) agg_b[rb * 224 + 200 + lane] = 0;
    }
}

// ---------------- bf16 MFMA GEMM: out[r][0..199] (+)= A_bf16[r][lda] @ Wb[208][K]^T ----------------
// block = 256 (4 waves); wave w: rows blockIdx*64 + w*16 .. +15; 13 col tiles (208)
// lda = runtime A row stride (>= KSTEPS*32); weights always dense [208][KSTEPS*32]
template<int KSTEPS, bool BIAS, bool ACC, bool DEGMASK>
__launch_bounds__(256)
__global__ void k_mgemm(const short* __restrict__ A, const short* __restrict__ Wb,
                        const float* __restrict__ bias, const int* __restrict__ degoffs,
                        float* __restrict__ out, int rows, int lda) {
    constexpr int LDW = KSTEPS * 32;
    const int t = threadIdx.x;
    const int wv = t >> 6, l = t & 63;
    const int lhi = l >> 4, llo = l & 15;
    const int rbase = blockIdx.x * 64 + wv * 16;
    f32x4 acc[13];
#pragma unroll
    for (int j = 0; j < 13; ++j) acc[j] = f32x4{0.f, 0.f, 0.f, 0.f};
    const short* arow = A + (size_t)(rbase + llo) * lda + lhi * 8;
#pragma unroll
    for (int kt = 0; kt < KSTEPS; ++kt) {
        bf16x8 a = *(const bf16x8*)(arow + kt * 32);
#pragma unroll
        for (int j = 0; j < 13; ++j) {
            bf16x8 b = *(const bf16x8*)(Wb + (size_t)(j * 16 + llo) * LDW + kt * 32 + lhi * 8);
            acc[j] = __builtin_amdgcn_mfma_f32_16x16x32_bf16(a, b, acc[j], 0, 0, 0);
        }
    }
    const int r0 = rbase + lhi * 4;
#pragma unroll
    for (int e = 0; e < 4; ++e) {
        int r = r0 + e;
        if (r >= rows) continue;
        float dm = 1.f;
        if (DEGMASK) dm = (degoffs[r + 1] - degoffs[r] == 0) ? 0.f : 1.f;
        float* orow = out + (size_t)r * 200;
#pragma unroll
        for (int j = 0; j < 13; ++j) {
            int d = j * 16 + llo;
            if (d < 200) {
                float v = acc[j][e] * dm;
                if (BIAS) v += bias[d];
                if (ACC) v += orow[d];
                orow[d] = v;
            }
        }
    }
}

// ---------------- weight prep: f32 -> padded bf16 [208][Kpad] ----------------
// mode 0: Wb[d][k] = W[d][koff+k] for k<Klen
// mode 1 (hop1 agg block-diag): h=d/100; Wb[d][h*112+kk] = W[d][koff+kk], kk<100
__global__ void k_prepw(const float* __restrict__ W, int ldW, int koff, int Klen, int Kpad,
                        int mode, short* __restrict__ Wb) {
    int id = blockIdx.x * 256 + threadIdx.x;
    int tot = 208 * Kpad;
    if (id >= tot) return;
    int d = id / Kpad, k = id - d * Kpad;
    float v = 0.f;
    if (d < 200) {
        if (mode == 0) { if (k < Klen) v = W[(size_t)d * ldW + koff + k]; }
        else { int h = d / 100; int kk = k - h * 112; if (kk >= 0 && kk < 100) v = W[(size_t)d * ldW + koff + kk]; }
    }
    Wb[id] = f2bf(v);
}

// combined [Wr | 0pad | Wf] -> bf16 [208][448]  (cols 0..99 = Wr, 128..427 = Wf)
__global__ void k_prepwrf(const float* __restrict__ Wr, const float* __restrict__ Wf,
                          short* __restrict__ Wb) {
    int id = blockIdx.x * 256 + threadIdx.x;
    if (id >= 208 * 448) return;
    int d = id / 448, k = id - d * 448;
    float v = 0.f;
    if (d < 200) {
        if (k < 100) v = Wr[(size_t)d * 100 + k];
        else if (k >= 128 && k < 428) v = Wf[(size_t)d * 300 + (k - 128)];
    }
    Wb[id] = f2bf(v);
}

__global__ void k_brf(const float* __restrict__ br, const float* __restrict__ bf,
                      float* __restrict__ brf) {
    int d = threadIdx.x;
    if (d < 200) brf[d] = br[d] + bf[d];
}

// ---------------- chunk converts ----------------
__global__ void k_xcb(const float* __restrict__ x, const float* __restrict__ invn,
                      short* __restrict__ sb, int rows) {
    int id = blockIdx.x * 256 + threadIdx.x;
    if (id >= rows * 128) return;
    int r = id >> 7, k = id & 127;
    sb[id] = f2bf(k < 100 ? x[(size_t)r * 100 + k] * invn[r] : 0.f);
}

// g [rows][100] f32 -> bf16 into combo buffer cols 0..127 (row stride 448)
__global__ void k_gcb(const float* __restrict__ g, short* __restrict__ gb, int rows) {
    int id = blockIdx.x * 256 + threadIdx.x;
    if (id >= rows * 128) return;
    int r = id >> 7, k = id & 127;
    gb[(size_t)r * 448 + k] = f2bf(k < 100 ? g[(size_t)r * 100 + k] : 0.f);
}

__global__ void k_h1b(const float* __restrict__ h1, short* __restrict__ sb, int rows) {
    int id = blockIdx.x * 256 + threadIdx.x;
    if (id >= rows * 224) return;
    int r = id / 224, k = id - r * 224;
    sb[id] = f2bf(k < 200 ? h1[(size_t)r * 200 + k] : 0.f);
}

// ---------------- GAT epilogue: elu + per-(node,head) l2norm -> bf16 padded ----------------
template<int DH, int H>
__global__ void gat_post2(const float* __restrict__ hb, short* __restrict__ pb, int rowsH) {
    int nh = blockIdx.x * 4 + (threadIdx.x >> 6);
    int lane = threadIdx.x & 63;
    if (nh >= rowsH) return;
    const float* p = hb + (size_t)nh * DH;
    constexpr int MM = (DH + 63) / 64;
    float v[MM];
    float ss = 0.f;
#pragma unroll
    for (int m = 0; m < MM; ++m) {
        int d = lane + m * 64;
        v[m] = 0.f;
        if (d < DH) { v[m] = eluf(p[d]); ss += v[m] * v[m]; }
    }
    ss = waveSum(ss);
    float inv = 1.f / fmaxf(sqrtf(ss), WEPS);
    short* ob = pb + (size_t)(nh / H) * 224 + (size_t)(nh % H) * DH;
#pragma unroll
    for (int m = 0; m < MM; ++m) {
        int d = lane + m * 64;
        if (d < DH) ob[d] = f2bf(v[m] * inv);
    }
}

// ---------------- merge combine ----------------
__global__ void merge_comb(const float* __restrict__ hi, const float* __restrict__ ho,
                           const float* __restrict__ Wl, const float* __restrict__ bl,
                           float* __restrict__ out, int N) {
    int wid = blockIdx.x * 4 + (threadIdx.x >> 6);
    int lane = threadIdx.x & 63;
    if (wid >= N) return;
    float vi[4], vo[4];
    float s = 0.f;
#pragma unroll
    for (int m = 0; m < 4; ++m) {
        int d = lane + m * 64;
        vi[m] = 0.f; vo[m] = 0.f;
        if (d < 200) {
            vi[m] = hi[(size_t)wid * 200 + d];
            vo[m] = ho[(size_t)wid * 200 + d];
            s += Wl[d] * vi[m] + Wl[200 + d] * vo[m];
        }
    }
    s = waveSum(s);
    float lam = 1.f / (1.f + expf(-(s + bl[0])));
    float hv[4];
    float ss = 0.f;
#pragma unroll
    for (int m = 0; m < 4; ++m) {
        int d = lane + m * 64;
        hv[m] = 0.f;
        if (d < 200) {
            float h = lam * vi[m] + (1.f - lam) * vo[m];
            hv[m] = eluf(h);
            ss += hv[m] * hv[m];
        }
    }
    ss = waveSum(ss);
    float inv = 1.f / fmaxf(sqrtf(ss), WEPS);
#pragma unroll
    for (int m = 0; m < 4; ++m) {
        int d = lane + m * 64;
        if (d < 200) out[(size_t)wid * 200 + d] = hv[m] * inv;
    }
}

// ---------------- relation layer: wave per type ----------------
// ge[m] = sum over edges of type m of [x_n[row], x_n[col]] ; g part = deg * g[m]
// write elu(l2norm(ge)) as bf16 into combo buffer cols 128..447 (row stride 448)
__global__ void k_gedges_w(const int* __restrict__ eidx, const int* __restrict__ listsT,
                           const int* __restrict__ offsT,
                           const float* __restrict__ x, const float* __restrict__ invn,
                           const float* __restrict__ g, short* __restrict__ gcomb,
                           int M, int E) {
    int m = blockIdx.x * 4 + (threadIdx.x >> 6);
    int lane = threadIdx.x & 63;
    if (m >= M) return;
    int o = offsT[m];
    int deg = offsT[m + 1] - o;
    float acc[5];
#pragma unroll
    for (int j = 0; j < 5; ++j) acc[j] = 0.f;
    for (int i = 0; i < deg; ++i) {
        int e = listsT[o + i];
        int r = eidx[e];
        int c = eidx[E + e];
        float ir = invn[r], ic = invn[c];
#pragma unroll
        for (int j = 0; j < 4; ++j) {
            int d = lane + j * 64;
            if (d < 100) acc[j] += x[(size_t)r * 100 + d] * ir;
            else if (d < 200) acc[j] += x[(size_t)c * 100 + d - 100] * ic;
        }
    }
#pragma unroll
    for (int j = 3; j < 5; ++j) {
        int d = lane + j * 64;
        if (d >= 200 && d < 300) acc[j] = (float)deg * g[(size_t)m * 100 + (d - 200)];
    }
    float ss = 0.f;
#pragma unroll
    for (int j = 0; j < 5; ++j) ss += acc[j] * acc[j];
    ss = waveSum(ss);
    float inv = 1.f / fmaxf(sqrtf(ss), WEPS);
    short* orow = gcomb + (size_t)m * 448 + 128;
#pragma unroll
    for (int j = 0; j < 5; ++j) {
        int d = lane + j * 64;
        if (d < 300) orow[d] = f2bf(eluf(acc[j] * inv));
        else if (d < 320) orow[d] = 0;
    }
}

// ---------------- host launch ----------------
extern "C" void kernel_launch(void* const* d_in, const int* in_sizes, int n_in,
                              void* d_out, int out_size, void* d_ws, size_t ws_size,
                              hipStream_t stream) {
    const int* eidx   = (const int*)d_in[0];
    const int* etype  = (const int*)d_in[1];
    const float* x    = (const float*)d_in[5];
    const float* g    = (const float*)d_in[6];
    const float* W_in1  = (const float*)d_in[7];
    const float* att_in1 = (const float*)d_in[8];
    const float* W_out1 = (const float*)d_in[9];
    const float* att_out1 = (const float*)d_in[10];
    const float* Wi1 = (const float*)d_in[11]; const float* bi1 = (const float*)d_in[12];
    const float* Wo1 = (const float*)d_in[13]; const float* bo1 = (const float*)d_in[14];
    const float* Wl1 = (const float*)d_in[15]; const float* bl1 = (const float*)d_in[16];
    const float* Wr  = (const float*)d_in[17]; const float* br  = (const float*)d_in[18];
    const float* Wf  = (const float*)d_in[19]; const float* bf  = (const float*)d_in[20];
    const float* W_in2  = (const float*)d_in[21]; const float* att_in2 = (const float*)d_in[22];
    const float* W_out2 = (const float*)d_in[23]; const float* att_out2 = (const float*)d_in[24];
    const float* Wi2 = (const float*)d_in[25]; const float* bi2 = (const float*)d_in[26];
    const float* Wo2 = (const float*)d_in[27]; const float* bo2 = (const float*)d_in[28];
    const float* Wl2 = (const float*)d_in[29]; const float* bl2 = (const float*)d_in[30];
    const float* W_ent = (const float*)d_in[31];

    const int E = in_sizes[1];
    const int N = in_sizes[5] / 100;
    const int M = in_sizes[6] / 100;
    const int Mr = (M + 63) & ~63;   // 64-row padded M for MFMA row tiles
    float* out = (float*)d_out;
    const int* row = eidx;
    const int* col = eidx + E;

    char* w = (char*)d_ws;
    size_t off_b = 0;
    auto alloc = [&](size_t bytes) -> void* {
        void* p = w + off_b;
        off_b += (bytes + 255) & ~(size_t)255;
        return p;
    };
    float* invn  = (float*)alloc((size_t)N * 4);
    float* h1    = (float*)alloc((size_t)N * 200 * 4);
    int* offs_in = (int*)alloc((size_t)(N + 1) * 4);
    int* lists_in= (int*)alloc((size_t)E * 4);
    int* offs_out= (int*)alloc((size_t)(N + 1) * 4);
    int* lists_out=(int*)alloc((size_t)E * 4);
    int* offsT   = (int*)alloc((size_t)(M + 1) * 4);
    int* listsT  = (int*)alloc((size_t)E * 4);
    int* cnt     = (int*)alloc((size_t)N * 4);
    int* cur     = (int*)alloc((size_t)N * 4);
    int* bsum    = (int*)alloc((size_t)64 * 4);
    float* wa_in = (float*)alloc((size_t)1200 * 4);
    float* wa_out= (float*)alloc((size_t)1200 * 4);
    float* rdot_in = (float*)alloc((size_t)N * 2 * 4);
    float* cdot_in = (float*)alloc((size_t)N * 2 * 4);
    float* rdot_out= (float*)alloc((size_t)N * 2 * 4);
    float* cdot_out= (float*)alloc((size_t)N * 2 * 4);
    float* gdot_in = (float*)alloc((size_t)M * 2 * 4);
    float* gdot_out= (float*)alloc((size_t)M * 2 * 4);
    float* ew_in   = (float*)alloc((size_t)E * 2 * 4);
    float* ew_out  = (float*)alloc((size_t)E * 2 * 4);
    float* pg_in   = (float*)alloc((size_t)M * 200 * 4);
    float* pg_out  = (float*)alloc((size_t)M * 200 * 4);
    float* gp      = (float*)alloc((size_t)M * 200 * 4);
    // combo bf16 buffer [Mr][448]: cols 0..127 = bf16(g), cols 128..447 = bf16(ge_n)
    // reused in hop2 as gp bf16 [Mr][224]
    short* gcomb   = (short*)alloc((size_t)Mr * 448 * 2);
    // bf16 weight buffers
    short* Ws_in1  = (short*)alloc((size_t)208 * 128 * 2);
    short* Ws_out1 = (short*)alloc((size_t)208 * 128 * 2);
    short* Wa_in1  = (short*)alloc((size_t)208 * 224 * 2);
    short* Wa_out1 = (short*)alloc((size_t)208 * 224 * 2);
    short* Wm_i1   = (short*)alloc((size_t)208 * 224 * 2);
    short* Wm_o1   = (short*)alloc((size_t)208 * 224 * 2);
    short* Ws_in2  = (short*)alloc((size_t)208 * 224 * 2);
    short* Ws_out2 = (short*)alloc((size_t)208 * 224 * 2);
    short* Wa_in2  = (short*)alloc((size_t)208 * 224 * 2);
    short* Wa_out2 = (short*)alloc((size_t)208 * 224 * 2);
    short* Wm_i2   = (short*)alloc((size_t)208 * 224 * 2);
    short* Wm_o2   = (short*)alloc((size_t)208 * 224 * 2);
    short* Wb_ent  = (short*)alloc((size_t)208 * 128 * 2);
    short* Wg_in1  = (short*)alloc((size_t)208 * 128 * 2);
    short* Wg_out1 = (short*)alloc((size_t)208 * 128 * 2);
    short* Wg_in2  = (short*)alloc((size_t)208 * 224 * 2);
    short* Wg_out2 = (short*)alloc((size_t)208 * 224 * 2);
    short* Wrf_b   = (short*)alloc((size_t)208 * 448 * 2);
    float* brf     = (float*)alloc((size_t)200 * 4);

    // chunk buffers from remaining ws (per-row: 800+800+448+448+448 = 2944B)
    if (off_b >= ws_size) return;
    size_t rem = ws_size - off_b;
    long long Cll = (long long)(rem / 3072);
    long long Nr64 = ((long long)N + 63) & ~63LL;
    int C = (int)(Cll > Nr64 ? Nr64 : Cll);
    C &= ~63;
    if (C < 64) return;
    float* hbA   = (float*)alloc((size_t)C * 200 * 4);
    float* hbB   = (float*)alloc((size_t)C * 200 * 4);
    short* agg_b = (short*)alloc((size_t)C * 224 * 2);
    short* post_b= (short*)alloc((size_t)C * 224 * 2);
    short* sb    = (short*)alloc((size_t)C * 224 * 2);
    if (off_b > ws_size) return;

    const int gE = (E + 255) / 256;
    const int gN4 = (N + 3) / 4;
    const int gM64 = (M + 63) / 64;
    const int gM4 = (M + 3) / 4;

    k_invnorm<<<gN4, 256, 0, stream>>>(x, invn, N);

    // zero pad region of post_b once (gat_post2 never writes k>=200)
    hipMemsetAsync(post_b, 0, (size_t)C * 224 * 2, stream);

    // ---- weight prep ----
    const int gW224 = (208 * 224 + 255) / 256;
    const int gW128 = (208 * 128 + 255) / 256;
    const int gW448 = (208 * 448 + 255) / 256;
    k_prepw<<<gW128, 256, 0, stream>>>(W_in1, 300, 100, 100, 128, 0, Ws_in1);
    k_prepw<<<gW128, 256, 0, stream>>>(W_out1, 300, 0, 100, 128, 0, Ws_out1);
    k_prepw<<<gW224, 256, 0, stream>>>(W_in1, 300, 0, 100, 224, 1, Wa_in1);
    k_prepw<<<gW224, 256, 0, stream>>>(W_out1, 300, 100, 100, 224, 1, Wa_out1);
    k_prepw<<<gW224, 256, 0, stream>>>(Wi1, 200, 0, 200, 224, 0, Wm_i1);
    k_prepw<<<gW224, 256, 0, stream>>>(Wo1, 200, 0, 200, 224, 0, Wm_o1);
    k_prepw<<<gW224, 256, 0, stream>>>(W_in2, 600, 200, 200, 224, 0, Ws_in2);
    k_prepw<<<gW224, 256, 0, stream>>>(W_out2, 600, 0, 200, 224, 0, Ws_out2);
    k_prepw<<<gW224, 256, 0, stream>>>(W_in2, 600, 0, 200, 224, 0, Wa_in2);
    k_prepw<<<gW224, 256, 0, stream>>>(W_out2, 600, 200, 200, 224, 0, Wa_out2);
    k_prepw<<<gW224, 256, 0, stream>>>(Wi2, 200, 0, 200, 224, 0, Wm_i2);
    k_prepw<<<gW224, 256, 0, stream>>>(Wo2, 200, 0, 200, 224, 0, Wm_o2);
    k_prepw<<<gW128, 256, 0, stream>>>(W_ent, 100, 0, 100, 128, 0, Wb_ent);
    // g-projection weight blocks (hop1: W[:,200:300]; hop2: W[:,400:600])
    k_prepw<<<gW128, 256, 0, stream>>>(W_in1, 300, 200, 100, 128, 0, Wg_in1);
    k_prepw<<<gW128, 256, 0, stream>>>(W_out1, 300, 200, 100, 128, 0, Wg_out1);
    k_prepw<<<gW224, 256, 0, stream>>>(W_in2, 600, 400, 200, 224, 0, Wg_in2);
    k_prepw<<<gW224, 256, 0, stream>>>(W_out2, 600, 400, 200, 224, 0, Wg_out2);
    // relation combined weight [Wr | Wf] and bias br+bf
    k_prepwrf<<<gW448, 256, 0, stream>>>(Wr, Wf, Wrf_b);
    k_brf<<<1, 256, 0, stream>>>(br, bf, brf);

    // ---- CSR builds: by col (in), by row (out), by etype ----
    int nbN = (N + SCAN_CHUNK - 1) / SCAN_CHUNK;
    int nbM = (M + SCAN_CHUNK - 1) / SCAN_CHUNK;
    hipMemsetAsync(cnt, 0, (size_t)N * 4, stream);
    k_count<<<gE, 256, 0, stream>>>(col, cnt, E);
    k_blocksum<<<nbN, 256, 0, stream>>>(cnt, bsum, N);
    k_scanwrite<<<nbN, 256, 0, stream>>>(cnt, bsum, offs_in, cur, N, nbN);
    k_scatter<<<gE, 256, 0, stream>>>(col, cur, lists_in, E);

    hipMemsetAsync(cnt, 0, (size_t)N * 4, stream);
    k_count<<<gE, 256, 0, stream>>>(row, cnt, E);
    k_blocksum<<<nbN, 256, 0, stream>>>(cnt, bsum, N);
    k_scanwrite<<<nbN, 256, 0, stream>>>(cnt, bsum, offs_out, cur, N, nbN);
    k_scatter<<<gE, 256, 0, stream>>>(row, cur, lists_out, E);

    hipMemsetAsync(cnt, 0, (size_t)M * 4, stream);
    k_count<<<gE, 256, 0, stream>>>(etype, cnt, E);
    k_blocksum<<<nbM, 256, 0, stream>>>(cnt, bsum, M);
    k_scanwrite<<<nbM, 256, 0, stream>>>(cnt, bsum, offsT, cur, M, nbM);
    k_scatter<<<gE, 256, 0, stream>>>(etype, cur, listsT, E);

    // ---- hop 1 setup ----
    k_watt<<<(2 * 300 + 255) / 256, 256, 0, stream>>>(att_in1, W_in1, wa_in, 2, 100, 300);
    k_watt<<<(2 * 300 + 255) / 256, 256, 0, stream>>>(att_out1, W_out1, wa_out, 2, 100, 300);
    k_dots<false><<<gN4, 256, 0, stream>>>(x, invn, wa_in, rdot_in, cdot_in, N);
    k_dots<false><<<gN4, 256, 0, stream>>>(x, invn, wa_out, rdot_out, cdot_out, N);
    k_gdot<<<(M * 2 + 255) / 256, 256, 0, stream>>>(g, wa_in, gdot_in, M, 2, 100, 300);
    k_gdot<<<(M * 2 + 255) / 256, 256, 0, stream>>>(g, wa_out, gdot_out, M, 2, 100, 300);
    // pg via MFMA: bf16(g) into combo cols 0..127, then GEMM with W[:,200:300]
    k_gcb<<<((int)(((size_t)M * 128 + 255) / 256)), 256, 0, stream>>>(g, gcomb, M);
    k_mgemm<4, false, false, false><<<gM64, 256, 0, stream>>>(gcomb, Wg_in1, nullptr, nullptr, pg_in, M, 448);
    k_mgemm<4, false, false, false><<<gM64, 256, 0, stream>>>(gcomb, Wg_out1, nullptr, nullptr, pg_out, M, 448);
    k_ew<<<(E * 2 + 255) / 256, 256, 0, stream>>>(row, col, etype, rdot_in, cdot_in, gdot_in, ew_in, E, 2);
    k_ew<<<(E * 2 + 255) / 256, 256, 0, stream>>>(row, col, etype, rdot_out, cdot_out, gdot_out, ew_out, E, 2);

    for (int n0 = 0; n0 < N; n0 += C) {
        int rows = (N - n0 < C) ? (N - n0) : C;
        int n1 = n0 + rows;
        int ga = (rows + 3) / 4;
        int gb = (rows + 63) / 64;
        k_xcb<<<(rows * 128 + 255) / 256, 256, 0, stream>>>(x + (size_t)n0 * 100, invn + n0, sb, rows);
        // in-direction (ends=col, nbr=row)
        k_agg<2, false><<<ga, 256, 0, stream>>>(offs_in, lists_in, row, etype, ew_in, pg_in, x, invn, agg_b, hbA, n0, n1);
        k_mgemm<4, false, true, true><<<gb, 256, 0, stream>>>(sb, Ws_in1, nullptr, offs_in + n0, hbA, rows, 128);
        k_mgemm<7, false, true, false><<<gb, 256, 0, stream>>>(agg_b, Wa_in1, nullptr, nullptr, hbA, rows, 224);
        // out-direction (ends=row, nbr=col)
        k_agg<2, false><<<ga, 256, 0, stream>>>(offs_out, lists_out, col, etype, ew_out, pg_out, x, invn, agg_b, hbB, n0, n1);
        k_mgemm<4, false, true, true><<<gb, 256, 0, stream>>>(sb, Ws_out1, nullptr, offs_out + n0, hbB, rows, 128);
        k_mgemm<7, false, true, false><<<gb, 256, 0, stream>>>(agg_b, Wa_out1, nullptr, nullptr, hbB, rows, 224);
        // epilogues + merge GEMMs
        gat_post2<100, 2><<<(2 * rows + 3) / 4, 256, 0, stream>>>(hbA, post_b, 2 * rows);
        k_mgemm<7, true, false, false><<<gb, 256, 0, stream>>>(post_b, Wm_i1, bi1, nullptr, hbA, rows, 224);
        gat_post2<100, 2><<<(2 * rows + 3) / 4, 256, 0, stream>>>(hbB, post_b, 2 * rows);
        k_mgemm<7, true, false, false><<<gb, 256, 0, stream>>>(post_b, Wm_o1, bo1, nullptr, hbB, rows, 224);
        merge_comb<<<ga, 256, 0, stream>>>(hbA, hbB, Wl1, bl1, h1 + (size_t)n0 * 200, rows);
    }

    // ---- relation layer: wave-per-type segment sum + one fused GEMM ----
    k_gedges_w<<<gM4, 256, 0, stream>>>(eidx, listsT, offsT, x, invn, g, gcomb, M, E);
    k_mgemm<14, true, false, false><<<gM64, 256, 0, stream>>>(gcomb, Wrf_b, brf, nullptr, gp, M, 448);

    // ---- hop 2 setup ----
    k_watt<<<(600 + 255) / 256, 256, 0, stream>>>(att_in2, W_in2, wa_in, 1, 200, 600);
    k_watt<<<(600 + 255) / 256, 256, 0, stream>>>(att_out2, W_out2, wa_out, 1, 200, 600);
    k_dots<true><<<gN4, 256, 0, stream>>>(h1, nullptr, wa_in, rdot_in, cdot_in, N);
    k_dots<true><<<gN4, 256, 0, stream>>>(h1, nullptr, wa_out, rdot_out, cdot_out, N);
    k_gdot<<<(M + 255) / 256, 256, 0, stream>>>(gp, wa_in, gdot_in, M, 1, 200, 600);
    k_gdot<<<(M + 255) / 256, 256, 0, stream>>>(gp, wa_out, gdot_out, M, 1, 200, 600);
    // pg2 via MFMA: bf16(gp) reusing combo buffer as [M][224], GEMM with W[:,400:600]
    k_h1b<<<((int)(((size_t)M * 224 + 255) / 256)), 256, 0, stream>>>(gp, gcomb, M);
    k_mgemm<7, false, false, false><<<gM64, 256, 0, stream>>>(gcomb, Wg_in2, nullptr, nullptr, pg_in, M, 224);
    k_mgemm<7, false, false, false><<<gM64, 256, 0, stream>>>(gcomb, Wg_out2, nullptr, nullptr, pg_out, M, 224);
    k_ew<<<(E + 255) / 256, 256, 0, stream>>>(row, col, etype, rdot_in, cdot_in, gdot_in, ew_in, E, 1);
    k_ew<<<(E + 255) / 256, 256, 0, stream>>>(row, col, etype, rdot_out, cdot_out, gdot_out, ew_out, E, 1);

    for (int n0 = 0; n0 < N; n0 += C) {
        int rows = (N - n0 < C) ? (N - n0) : C;
        int n1 = n0 + rows;
        int ga = (rows + 3) / 4;
        int gb = (rows + 63) / 64;
        k_h1b<<<(rows * 224 + 255) / 256, 256, 0, stream>>>(h1 + (size_t)n0 * 200, sb, rows);
        k_agg<1, true><<<ga, 256, 0, stream>>>(offs_in, lists_in, row, etype, ew_in, pg_in, h1, nullptr, agg_b, hbA, n0, n1);
        k_mgemm<7, false, true, true><<<gb, 256, 0, stream>>>(sb, Ws_in2, nullptr, offs_in + n0, hbA, rows, 224);
        k_mgemm<7, false, true, false><<<gb, 256, 0, stream>>>(agg_b, Wa_in2, nullptr, nullptr, hbA, rows, 224);
        k_agg<1, true><<<ga, 256, 0, stream>>>(offs_out, lists_out, col, etype, ew_out, pg_out, h1, nullptr, agg_b, hbB, n0, n1);
        k_mgemm<7, false, true, true><<<gb, 256, 0, stream>>>(sb, Ws_out2, nullptr, offs_out + n0, hbB, rows, 224);
        k_mgemm<7, false, true, false><<<gb, 256, 0, stream>>>(agg_b, Wa_out2, nullptr, nullptr, hbB, rows, 224);
        gat_post2<200, 1><<<ga, 256, 0, stream>>>(hbA, post_b, rows);
        k_mgemm<7, true, false, false><<<gb, 256, 0, stream>>>(post_b, Wm_i2, bi2, nullptr, hbA, rows, 224);
        gat_post2<200, 1><<<ga, 256, 0, stream>>>(hbB, post_b, rows);
        k_mgemm<7, true, false, false><<<gb, 256, 0, stream>>>(post_b, Wm_o2, bo2, nullptr, hbB, rows, 224);
        merge_comb<<<ga, 256, 0, stream>>>(hbA, hbB, Wl2, bl2, out + (size_t)n0 * 200, rows);
        // entity residual for this chunk: out += l2norm(x) @ W_ent^T
        k_xcb<<<(rows * 128 + 255) / 256, 256, 0, stream>>>(x + (size_t)n0 * 100, invn + n0, sb, rows);
        k_mgemm<4, false, true, false><<<gb, 256, 0, stream>>>(sb, Wb_ent, nullptr, nullptr, out + (size_t)n0 * 200, rows, 128);
    }
}

// Round 2
// 2958.364 us; speedup vs baseline: 1.2210x; 1.2210x over previous
//
#include <hip/hip_runtime.h>
#include <cstddef>
#include <cstdint>

#define WSLOPE 0.2f
#define WEPS 1e-12f

typedef __attribute__((ext_vector_type(8))) short bf16x8;
typedef __attribute__((ext_vector_type(4))) float f32x4;

__device__ __forceinline__ float waveSum(float v) {
#pragma unroll
    for (int off = 32; off > 0; off >>= 1) v += __shfl_xor(v, off, 64);
    return v;
}
__device__ __forceinline__ float eluf(float v) { return v > 0.f ? v : expm1f(v); }
__device__ __forceinline__ short f2bf(float f) {
    union { float f; uint32_t u; } v; v.f = f;
    uint32_t r = v.u + 0x7FFF + ((v.u >> 16) & 1);
    return (short)(r >> 16);
}

// ---------------- per-node inverse L2 norm of x ----------------
__global__ void k_invnorm(const float* __restrict__ x, float* __restrict__ invn, int N) {
    int wid = blockIdx.x * 4 + (threadIdx.x >> 6);
    int lane = threadIdx.x & 63;
    if (wid >= N) return;
    const float* p = x + (size_t)wid * 100;
    float a = p[lane];
    float ss = a * a;
    if (lane < 36) { float b = p[lane + 64]; ss += b * b; }
    ss = waveSum(ss);
    if (lane == 0) invn[wid] = 1.f / fmaxf(sqrtf(ss), WEPS);
}

// ---------------- generic CSR build (counting sort) ----------------
__global__ void k_count(const int* __restrict__ keys, int* __restrict__ cnt, int n) {
    int i = blockIdx.x * 256 + threadIdx.x;
    if (i < n) atomicAdd(&cnt[keys[i]], 1);
}

#define SCAN_CHUNK 2048
__global__ void k_blocksum(const int* __restrict__ cnt, int* __restrict__ bsum, int n) {
    __shared__ int sh[256];
    int b = blockIdx.x, t = threadIdx.x;
    int base = b * SCAN_CHUNK;
    int s = 0;
    for (int i = t; i < SCAN_CHUNK; i += 256) { int idx = base + i; if (idx < n) s += cnt[idx]; }
    sh[t] = s; __syncthreads();
    for (int off = 128; off > 0; off >>= 1) { if (t < off) sh[t] += sh[t + off]; __syncthreads(); }
    if (t == 0) bsum[b] = sh[0];
}

__global__ void k_scanwrite(const int* __restrict__ cnt, const int* __restrict__ bsum,
                            int* __restrict__ offs, int* __restrict__ cur, int n, int nb) {
    __shared__ int sh[256];
    __shared__ int sbase;
    int b = blockIdx.x, t = threadIdx.x;
    if (t == 0) { int s = 0; for (int i = 0; i < b; ++i) s += bsum[i]; sbase = s; }
    __syncthreads();
    int base = b * SCAN_CHUNK;
    int loc[8]; int ts = 0;
#pragma unroll
    for (int i = 0; i < 8; ++i) { int idx = base + t * 8 + i; int v = (idx < n) ? cnt[idx] : 0; loc[i] = ts; ts += v; }
    sh[t] = ts; __syncthreads();
    for (int off = 1; off < 256; off <<= 1) {
        int v = (t >= off) ? sh[t - off] : 0;
        __syncthreads();
        sh[t] += v;
        __syncthreads();
    }
    int excl = (t == 0) ? 0 : sh[t - 1];
    int gbase = sbase + excl;
#pragma unroll
    for (int i = 0; i < 8; ++i) {
        int idx = base + t * 8 + i;
        if (idx < n) { offs[idx] = gbase + loc[i]; cur[idx] = gbase + loc[i]; }
    }
    if (b == nb - 1 && t == 255) offs[n] = sbase + sh[255];
}

// scatter with payload: sorted neighbor / etype / key arrays (kills one indirection)
__global__ void k_scatter3(const int* __restrict__ keys, const int* __restrict__ other,
                           const int* __restrict__ et, int* __restrict__ cur,
                           int* __restrict__ nbrS, int* __restrict__ etS,
                           int* __restrict__ keyS, int n) {
    int i = blockIdx.x * 256 + threadIdx.x;
    if (i < n) {
        int p = atomicAdd(&cur[keys[i]], 1);
        nbrS[p] = other[i];
        etS[p] = et[i];
        keyS[p] = keys[i];
    }
}

// scatter for etype sort: store both endpoints in sorted order
__global__ void k_scatter2(const int* __restrict__ keys, int* __restrict__ cur,
                           int* __restrict__ rs, int* __restrict__ cs,
                           const int* __restrict__ row, const int* __restrict__ col, int n) {
    int i = blockIdx.x * 256 + threadIdx.x;
    if (i < n) {
        int p = atomicAdd(&cur[keys[i]], 1);
        rs[p] = row[i];
        cs[p] = col[i];
    }
}

// ---------------- attention vector ----------------
__global__ void k_watt(const float* __restrict__ att, const float* __restrict__ W,
                       float* __restrict__ wa, int H, int DH, int K) {
    int id = blockIdx.x * 256 + threadIdx.x;
    if (id >= H * K) return;
    int h = id / K, k = id % K;
    float s = 0.f;
    for (int j = 0; j < DH; ++j) s += att[h * DH + j] * W[(size_t)(h * DH + j) * K + k];
    wa[id] = s;
}

// ---------------- per-node partial dots ----------------
template<bool HOP2>
__global__ void k_dots(const float* __restrict__ feat, const float* __restrict__ invn,
                       const float* __restrict__ wa, float* __restrict__ rdot,
                       float* __restrict__ cdot, int N) {
    int wid = blockIdx.x * 4 + (threadIdx.x >> 6);
    int lane = threadIdx.x & 63;
    if (wid >= N) return;
    if (!HOP2) {
        float inv = invn[wid];
        const float* p = feat + (size_t)wid * 100;
        float f0 = p[lane] * inv;
        float f1 = (lane < 36) ? p[lane + 64] * inv : 0.f;
#pragma unroll
        for (int h = 0; h < 2; ++h) {
            const float* w = wa + h * 300;
            float r = f0 * w[lane] + ((lane < 36) ? f1 * w[lane + 64] : 0.f);
            float c = f0 * w[100 + lane] + ((lane < 36) ? f1 * w[100 + lane + 64] : 0.f);
            r = waveSum(r); c = waveSum(c);
            if (lane == 0) { rdot[wid * 2 + h] = r; cdot[wid * 2 + h] = c; }
        }
    } else {
        const float* p = feat + (size_t)wid * 200;
        float r = 0.f, c = 0.f;
#pragma unroll
        for (int m = 0; m < 4; ++m) {
            int d = lane + m * 64;
            if (d < 200) { float f = p[d]; r += f * wa[d]; c += f * wa[200 + d]; }
        }
        r = waveSum(r); c = waveSum(c);
        if (lane == 0) { rdot[wid] = r; cdot[wid] = c; }
    }
}

// ---------------- per-type dot ----------------
__global__ void k_gdot(const float* __restrict__ gsrc, const float* __restrict__ wa,
                       float* __restrict__ gdot, int M, int H, int GL, int K) {
    int id = blockIdx.x * 256 + threadIdx.x;
    if (id >= M * H) return;
    int m = id / H, h = id % H;
    float s = 0.f;
    const float* w = wa + h * K + 2 * GL;
    const float* gm = gsrc + (size_t)m * GL;
    for (int kk = 0; kk < GL; ++kk) s += gm[kk] * w[kk];
    gdot[id] = s;
}

// ---------------- per-edge weight, written in CSR-sorted order ----------------
__global__ void k_ew_s(const int* __restrict__ nbrS, const int* __restrict__ keyS,
                       const int* __restrict__ etS,
                       const float* __restrict__ ndot, const float* __restrict__ kdot,
                       const float* __restrict__ gdot, float* __restrict__ ewS, int E, int H) {
    int id = blockIdx.x * 256 + threadIdx.x;
    if (id >= E * H) return;
    int p = id / H, h = id - p * H;
    float a = ndot[nbrS[p] * H + h] + kdot[keyS[p] * H + h] + gdot[etS[p] * H + h];
    float lr = a > 0.f ? a : WSLOPE * a;
    ewS[id] = expf(-lr);
}

// ---------------- CSR aggregation: wave per node (sorted streams) ----------------
template<int H, bool HOP2>
__global__ void k_agg(const int* __restrict__ offs, const int* __restrict__ nbrS,
                      const int* __restrict__ etS, const float* __restrict__ ewS,
                      const float* __restrict__ projg,
                      const float* __restrict__ feat, const float* __restrict__ invn,
                      short* __restrict__ agg_b, float* __restrict__ hb, int n0, int n1) {
    int node = n0 + blockIdx.x * 4 + (threadIdx.x >> 6);
    int lane = threadIdx.x & 63;
    if (node >= n1) return;
    int o = offs[node];
    int deg = offs[node + 1] - o;
    float va[7];
#pragma unroll
    for (int m = 0; m < 7; ++m) va[m] = 0.f;
    if (deg > 0) {
        float s0 = 0.f, s1 = 0.f;
        for (int i = lane; i < deg; i += 64) {
            s0 += ewS[(size_t)(o + i) * H];
            if (H == 2) s1 += ewS[(size_t)(o + i) * H + 1];
        }
        s0 = waveSum(s0);
        float rd0 = 1.f / s0, rd1 = rd0;
        if (H == 2) { s1 = waveSum(s1); rd1 = 1.f / s1; }
        for (int j = 0; j < deg; ++j) {
            float a0 = ewS[(size_t)(o + j) * H] * rd0;
            float a1 = (H == 2) ? ewS[(size_t)(o + j) * H + 1] * rd1 : a0;
            int nbr = nbrS[o + j];
            int et = etS[o + j];
            const float* pgr = projg + (size_t)et * 200;
            if (!HOP2) {
                float inv = invn[nbr];
                const float* fr = feat + (size_t)nbr * 100;
#pragma unroll
                for (int m = 0; m < 7; ++m) {
                    int d = lane + m * 64;
                    if (d < 200) {
                        int kk = d >= 100 ? d - 100 : d;
                        float al = d < 100 ? a0 : a1;
                        va[m] += al * fr[kk] * inv;
                    } else if (d < 400) {
                        int dd = d - 200;
                        float al = dd < 100 ? a0 : a1;
                        va[m] += al * pgr[dd];
                    }
                }
            } else {
                const float* fr = feat + (size_t)nbr * 200;
#pragma unroll
                for (int m = 0; m < 7; ++m) {
                    int d = lane + m * 64;
                    if (d < 200) va[m] += a0 * fr[d];
                    else if (d < 400) va[m] += a0 * pgr[d - 200];
                }
            }
        }
    }
    size_t rb = (size_t)(node - n0);
#pragma unroll
    for (int m = 0; m < 7; ++m) {
        int d = lane + m * 64;
        if (d < 200) {
            int slot = HOP2 ? d : (d < 100 ? d : d + 12);
            agg_b[rb * 224 + slot] = f2bf(va[m]);
        } else if (d < 400) {
            hb[rb * 200 + (d - 200)] = va[m];
        }
    }
    // zero the pad slots of this row
    if (!HOP2) {
        if (lane < 24) { int s = lane < 12 ? 100 + lane : 200 + lane; agg_b[rb * 224 + s] = 0; }
    } else {
        if (lane < 24) agg_b[rb * 224 + 200 + lane] = 0;
    }
}

// ---------------- bf16 MFMA GEMM: out[r][0..199] (+)= A_bf16[r][lda] @ Wb[208][K]^T ----------------
template<int KSTEPS, bool BIAS, bool ACC, bool DEGMASK>
__launch_bounds__(256)
__global__ void k_mgemm(const short* __restrict__ A, const short* __restrict__ Wb,
                        const float* __restrict__ bias, const int* __restrict__ degoffs,
                        float* __restrict__ out, int rows, int lda) {
    constexpr int LDW = KSTEPS * 32;
    const int t = threadIdx.x;
    const int wv = t >> 6, l = t & 63;
    const int lhi = l >> 4, llo = l & 15;
    const int rbase = blockIdx.x * 64 + wv * 16;
    f32x4 acc[13];
#pragma unroll
    for (int j = 0; j < 13; ++j) acc[j] = f32x4{0.f, 0.f, 0.f, 0.f};
    const short* arow = A + (size_t)(rbase + llo) * lda + lhi * 8;
#pragma unroll
    for (int kt = 0; kt < KSTEPS; ++kt) {
        bf16x8 a = *(const bf16x8*)(arow + kt * 32);
#pragma unroll
        for (int j = 0; j < 13; ++j) {
            bf16x8 b = *(const bf16x8*)(Wb + (size_t)(j * 16 + llo) * LDW + kt * 32 + lhi * 8);
            acc[j] = __builtin_amdgcn_mfma_f32_16x16x32_bf16(a, b, acc[j], 0, 0, 0);
        }
    }
    const int r0 = rbase + lhi * 4;
#pragma unroll
    for (int e = 0; e < 4; ++e) {
        int r = r0 + e;
        if (r >= rows) continue;
        float dm = 1.f;
        if (DEGMASK) dm = (degoffs[r + 1] - degoffs[r] == 0) ? 0.f : 1.f;
        float* orow = out + (size_t)r * 200;
#pragma unroll
        for (int j = 0; j < 13; ++j) {
            int d = j * 16 + llo;
            if (d < 200) {
                float v = acc[j][e] * dm;
                if (BIAS) v += bias[d];
                if (ACC) v += orow[d];
                orow[d] = v;
            }
        }
    }
}

// ---------------- weight prep: f32 -> padded bf16 [208][Kpad] ----------------
__global__ void k_prepw(const float* __restrict__ W, int ldW, int koff, int Klen, int Kpad,
                        int mode, short* __restrict__ Wb) {
    int id = blockIdx.x * 256 + threadIdx.x;
    int tot = 208 * Kpad;
    if (id >= tot) return;
    int d = id / Kpad, k = id - d * Kpad;
    float v = 0.f;
    if (d < 200) {
        if (mode == 0) { if (k < Klen) v = W[(size_t)d * ldW + koff + k]; }
        else { int h = d / 100; int kk = k - h * 112; if (kk >= 0 && kk < 100) v = W[(size_t)d * ldW + koff + kk]; }
    }
    Wb[id] = f2bf(v);
}

// combined [Wr | 0pad | Wf] -> bf16 [208][448]  (cols 0..99 = Wr, 128..427 = Wf)
__global__ void k_prepwrf(const float* __restrict__ Wr, const float* __restrict__ Wf,
                          short* __restrict__ Wb) {
    int id = blockIdx.x * 256 + threadIdx.x;
    if (id >= 208 * 448) return;
    int d = id / 448, k = id - d * 448;
    float v = 0.f;
    if (d < 200) {
        if (k < 100) v = Wr[(size_t)d * 100 + k];
        else if (k >= 128 && k < 428) v = Wf[(size_t)d * 300 + (k - 128)];
    }
    Wb[id] = f2bf(v);
}

__global__ void k_brf(const float* __restrict__ br, const float* __restrict__ bf,
                      float* __restrict__ brf) {
    int d = threadIdx.x;
    if (d < 200) brf[d] = br[d] + bf[d];
}

// ---------------- chunk converts ----------------
__global__ void k_xcb(const float* __restrict__ x, const float* __restrict__ invn,
                      short* __restrict__ sb, int rows) {
    int id = blockIdx.x * 256 + threadIdx.x;
    if (id >= rows * 128) return;
    int r = id >> 7, k = id & 127;
    sb[id] = f2bf(k < 100 ? x[(size_t)r * 100 + k] * invn[r] : 0.f);
}

// g [rows][100] f32 -> bf16 into combo buffer cols 0..127 (row stride 448)
__global__ void k_gcb(const float* __restrict__ g, short* __restrict__ gb, int rows) {
    int id = blockIdx.x * 256 + threadIdx.x;
    if (id >= rows * 128) return;
    int r = id >> 7, k = id & 127;
    gb[(size_t)r * 448 + k] = f2bf(k < 100 ? g[(size_t)r * 100 + k] : 0.f);
}

__global__ void k_h1b(const float* __restrict__ h1, short* __restrict__ sb, int rows) {
    int id = blockIdx.x * 256 + threadIdx.x;
    if (id >= rows * 224) return;
    int r = id / 224, k = id - r * 224;
    sb[id] = f2bf(k < 200 ? h1[(size_t)r * 200 + k] : 0.f);
}

// ---------------- GAT epilogue: elu + per-(node,head) l2norm -> bf16 padded ----------------
template<int DH, int H>
__global__ void gat_post2(const float* __restrict__ hb, short* __restrict__ pb, int rowsH) {
    int nh = blockIdx.x * 4 + (threadIdx.x >> 6);
    int lane = threadIdx.x & 63;
    if (nh >= rowsH) return;
    const float* p = hb + (size_t)nh * DH;
    constexpr int MM = (DH + 63) / 64;
    float v[MM];
    float ss = 0.f;
#pragma unroll
    for (int m = 0; m < MM; ++m) {
        int d = lane + m * 64;
        v[m] = 0.f;
        if (d < DH) { v[m] = eluf(p[d]); ss += v[m] * v[m]; }
    }
    ss = waveSum(ss);
    float inv = 1.f / fmaxf(sqrtf(ss), WEPS);
    short* ob = pb + (size_t)(nh / H) * 224 + (size_t)(nh % H) * DH;
#pragma unroll
    for (int m = 0; m < MM; ++m) {
        int d = lane + m * 64;
        if (d < DH) ob[d] = f2bf(v[m] * inv);
    }
}

// ---------------- merge combine ----------------
__global__ void merge_comb(const float* __restrict__ hi, const float* __restrict__ ho,
                           const float* __restrict__ Wl, const float* __restrict__ bl,
                           float* __restrict__ out, int N) {
    int wid = blockIdx.x * 4 + (threadIdx.x >> 6);
    int lane = threadIdx.x & 63;
    if (wid >= N) return;
    float vi[4], vo[4];
    float s = 0.f;
#pragma unroll
    for (int m = 0; m < 4; ++m) {
        int d = lane + m * 64;
        vi[m] = 0.f; vo[m] = 0.f;
        if (d < 200) {
            vi[m] = hi[(size_t)wid * 200 + d];
            vo[m] = ho[(size_t)wid * 200 + d];
            s += Wl[d] * vi[m] + Wl[200 + d] * vo[m];
        }
    }
    s = waveSum(s);
    float lam = 1.f / (1.f + expf(-(s + bl[0])));
    float hv[4];
    float ss = 0.f;
#pragma unroll
    for (int m = 0; m < 4; ++m) {
        int d = lane + m * 64;
        hv[m] = 0.f;
        if (d < 200) {
            float h = lam * vi[m] + (1.f - lam) * vo[m];
            hv[m] = eluf(h);
            ss += hv[m] * hv[m];
        }
    }
    ss = waveSum(ss);
    float inv = 1.f / fmaxf(sqrtf(ss), WEPS);
#pragma unroll
    for (int m = 0; m < 4; ++m) {
        int d = lane + m * 64;
        if (d < 200) out[(size_t)wid * 200 + d] = hv[m] * inv;
    }
}

// ---------------- relation layer: block per type (lane owns a dim) ----------------
// ge[m] = sum over edges of type m of [x_n[row], x_n[col]] ; g part = deg * g[m]
// write elu(l2norm(ge)) as bf16 into combo buffer cols 128..447 (row stride 448)
__global__ void k_gedges_b(const int* __restrict__ rsT, const int* __restrict__ csT,
                           const int* __restrict__ offsT,
                           const float* __restrict__ x, const float* __restrict__ invn,
                           const float* __restrict__ g, short* __restrict__ gcomb, int M) {
    __shared__ float red[4];
    int m = blockIdx.x, t = threadIdx.x;
    int o = offsT[m];
    int deg = offsT[m + 1] - o;
    float acc = 0.f;
    if (t < 100) {
        for (int i = 0; i < deg; ++i) {
            int r = rsT[o + i];
            acc += x[(size_t)r * 100 + t] * invn[r];
        }
    } else if (t < 200) {
        for (int i = 0; i < deg; ++i) {
            int c = csT[o + i];
            acc += x[(size_t)c * 100 + (t - 100)] * invn[c];
        }
    }
    float gval = 0.f;
    if (t < 100) gval = (float)deg * g[(size_t)m * 100 + t];
    float sq = acc * acc + gval * gval;
    sq = waveSum(sq);
    if ((t & 63) == 0) red[t >> 6] = sq;
    __syncthreads();
    float s2 = red[0] + red[1] + red[2] + red[3];
    float inv = 1.f / fmaxf(sqrtf(s2), WEPS);
    short* orow = gcomb + (size_t)m * 448 + 128;
    if (t < 200) orow[t] = f2bf(eluf(acc * inv));
    if (t < 100) orow[200 + t] = f2bf(eluf(gval * inv));
    if (t >= 200 && t < 220) orow[100 + t] = 0;   // pad cols 300..319
}

// ---------------- host launch ----------------
extern "C" void kernel_launch(void* const* d_in, const int* in_sizes, int n_in,
                              void* d_out, int out_size, void* d_ws, size_t ws_size,
                              hipStream_t stream) {
    const int* eidx   = (const int*)d_in[0];
    const int* etype  = (const int*)d_in[1];
    const float* x    = (const float*)d_in[5];
    const float* g    = (const float*)d_in[6];
    const float* W_in1  = (const float*)d_in[7];
    const float* att_in1 = (const float*)d_in[8];
    const float* W_out1 = (const float*)d_in[9];
    const float* att_out1 = (const float*)d_in[10];
    const float* Wi1 = (const float*)d_in[11]; const float* bi1 = (const float*)d_in[12];
    const float* Wo1 = (const float*)d_in[13]; const float* bo1 = (const float*)d_in[14];
    const float* Wl1 = (const float*)d_in[15]; const float* bl1 = (const float*)d_in[16];
    const float* Wr  = (const float*)d_in[17]; const float* br  = (const float*)d_in[18];
    const float* Wf  = (const float*)d_in[19]; const float* bf  = (const float*)d_in[20];
    const float* W_in2  = (const float*)d_in[21]; const float* att_in2 = (const float*)d_in[22];
    const float* W_out2 = (const float*)d_in[23]; const float* att_out2 = (const float*)d_in[24];
    const float* Wi2 = (const float*)d_in[25]; const float* bi2 = (const float*)d_in[26];
    const float* Wo2 = (const float*)d_in[27]; const float* bo2 = (const float*)d_in[28];
    const float* Wl2 = (const float*)d_in[29]; const float* bl2 = (const float*)d_in[30];
    const float* W_ent = (const float*)d_in[31];

    const int E = in_sizes[1];
    const int N = in_sizes[5] / 100;
    const int M = in_sizes[6] / 100;
    const int Mr = (M + 63) & ~63;   // 64-row padded M for MFMA row tiles
    float* out = (float*)d_out;
    const int* row = eidx;
    const int* col = eidx + E;

    char* w = (char*)d_ws;
    size_t off_b = 0;
    auto alloc = [&](size_t bytes) -> void* {
        void* p = w + off_b;
        off_b += (bytes + 255) & ~(size_t)255;
        return p;
    };
    float* invn  = (float*)alloc((size_t)N * 4);
    float* h1    = (float*)alloc((size_t)N * 200 * 4);
    int* offs_in = (int*)alloc((size_t)(N + 1) * 4);
    int* offs_out= (int*)alloc((size_t)(N + 1) * 4);
    int* offsT   = (int*)alloc((size_t)(M + 1) * 4);
    int* nbrS_in = (int*)alloc((size_t)E * 4);
    int* etS_in  = (int*)alloc((size_t)E * 4);
    int* keyS_in = (int*)alloc((size_t)E * 4);
    int* nbrS_out= (int*)alloc((size_t)E * 4);
    int* etS_out = (int*)alloc((size_t)E * 4);
    int* keyS_out= (int*)alloc((size_t)E * 4);
    int* rsT     = (int*)alloc((size_t)E * 4);
    int* csT     = (int*)alloc((size_t)E * 4);
    int* cnt     = (int*)alloc((size_t)N * 4);
    int* cur     = (int*)alloc((size_t)N * 4);
    int* bsum    = (int*)alloc((size_t)64 * 4);
    float* wa_in = (float*)alloc((size_t)1200 * 4);
    float* wa_out= (float*)alloc((size_t)1200 * 4);
    float* rdot_in = (float*)alloc((size_t)N * 2 * 4);
    float* cdot_in = (float*)alloc((size_t)N * 2 * 4);
    float* rdot_out= (float*)alloc((size_t)N * 2 * 4);
    float* cdot_out= (float*)alloc((size_t)N * 2 * 4);
    float* gdot_in = (float*)alloc((size_t)M * 2 * 4);
    float* gdot_out= (float*)alloc((size_t)M * 2 * 4);
    float* ewS_in  = (float*)alloc((size_t)E * 2 * 4);
    float* ewS_out = (float*)alloc((size_t)E * 2 * 4);
    float* pg_in   = (float*)alloc((size_t)M * 200 * 4);
    float* pg_out  = (float*)alloc((size_t)M * 200 * 4);
    float* gp      = (float*)alloc((size_t)M * 200 * 4);
    // combo bf16 buffer [Mr][448]: cols 0..127 = bf16(g), cols 128..447 = bf16(ge_n)
    // reused in hop2 as gp bf16 [Mr][224]
    short* gcomb   = (short*)alloc((size_t)Mr * 448 * 2);
    // bf16 weight buffers
    short* Ws_in1  = (short*)alloc((size_t)208 * 128 * 2);
    short* Ws_out1 = (short*)alloc((size_t)208 * 128 * 2);
    short* Wa_in1  = (short*)alloc((size_t)208 * 224 * 2);
    short* Wa_out1 = (short*)alloc((size_t)208 * 224 * 2);
    short* Wm_i1   = (short*)alloc((size_t)208 * 224 * 2);
    short* Wm_o1   = (short*)alloc((size_t)208 * 224 * 2);
    short* Ws_in2  = (short*)alloc((size_t)208 * 224 * 2);
    short* Ws_out2 = (short*)alloc((size_t)208 * 224 * 2);
    short* Wa_in2  = (short*)alloc((size_t)208 * 224 * 2);
    short* Wa_out2 = (short*)alloc((size_t)208 * 224 * 2);
    short* Wm_i2   = (short*)alloc((size_t)208 * 224 * 2);
    short* Wm_o2   = (short*)alloc((size_t)208 * 224 * 2);
    short* Wb_ent  = (short*)alloc((size_t)208 * 128 * 2);
    short* Wg_in1  = (short*)alloc((size_t)208 * 128 * 2);
    short* Wg_out1 = (short*)alloc((size_t)208 * 128 * 2);
    short* Wg_in2  = (short*)alloc((size_t)208 * 224 * 2);
    short* Wg_out2 = (short*)alloc((size_t)208 * 224 * 2);
    short* Wrf_b   = (short*)alloc((size_t)208 * 448 * 2);
    float* brf     = (float*)alloc((size_t)200 * 4);

    // chunk buffers from remaining ws (per-row: 800+800+448+448+448 = 2944B)
    if (off_b >= ws_size) return;
    size_t rem = ws_size - off_b;
    long long Cll = (long long)(rem / 3072);
    long long Nr64 = ((long long)N + 63) & ~63LL;
    int C = (int)(Cll > Nr64 ? Nr64 : Cll);
    C &= ~63;
    if (C < 64) return;
    float* hbA   = (float*)alloc((size_t)C * 200 * 4);
    float* hbB   = (float*)alloc((size_t)C * 200 * 4);
    short* agg_b = (short*)alloc((size_t)C * 224 * 2);
    short* post_b= (short*)alloc((size_t)C * 224 * 2);
    short* sb    = (short*)alloc((size_t)C * 224 * 2);
    if (off_b > ws_size) return;

    const int gE = (E + 255) / 256;
    const int gN4 = (N + 3) / 4;
    const int gM64 = (M + 63) / 64;

    k_invnorm<<<gN4, 256, 0, stream>>>(x, invn, N);

    // zero pad region of post_b once (gat_post2 never writes k>=200)
    hipMemsetAsync(post_b, 0, (size_t)C * 224 * 2, stream);

    // ---- weight prep ----
    const int gW224 = (208 * 224 + 255) / 256;
    const int gW128 = (208 * 128 + 255) / 256;
    const int gW448 = (208 * 448 + 255) / 256;
    k_prepw<<<gW128, 256, 0, stream>>>(W_in1, 300, 100, 100, 128, 0, Ws_in1);
    k_prepw<<<gW128, 256, 0, stream>>>(W_out1, 300, 0, 100, 128, 0, Ws_out1);
    k_prepw<<<gW224, 256, 0, stream>>>(W_in1, 300, 0, 100, 224, 1, Wa_in1);
    k_prepw<<<gW224, 256, 0, stream>>>(W_out1, 300, 100, 100, 224, 1, Wa_out1);
    k_prepw<<<gW224, 256, 0, stream>>>(Wi1, 200, 0, 200, 224, 0, Wm_i1);
    k_prepw<<<gW224, 256, 0, stream>>>(Wo1, 200, 0, 200, 224, 0, Wm_o1);
    k_prepw<<<gW224, 256, 0, stream>>>(W_in2, 600, 200, 200, 224, 0, Ws_in2);
    k_prepw<<<gW224, 256, 0, stream>>>(W_out2, 600, 0, 200, 224, 0, Ws_out2);
    k_prepw<<<gW224, 256, 0, stream>>>(W_in2, 600, 0, 200, 224, 0, Wa_in2);
    k_prepw<<<gW224, 256, 0, stream>>>(W_out2, 600, 200, 200, 224, 0, Wa_out2);
    k_prepw<<<gW224, 256, 0, stream>>>(Wi2, 200, 0, 200, 224, 0, Wm_i2);
    k_prepw<<<gW224, 256, 0, stream>>>(Wo2, 200, 0, 200, 224, 0, Wm_o2);
    k_prepw<<<gW128, 256, 0, stream>>>(W_ent, 100, 0, 100, 128, 0, Wb_ent);
    // g-projection weight blocks (hop1: W[:,200:300]; hop2: W[:,400:600])
    k_prepw<<<gW128, 256, 0, stream>>>(W_in1, 300, 200, 100, 128, 0, Wg_in1);
    k_prepw<<<gW128, 256, 0, stream>>>(W_out1, 300, 200, 100, 128, 0, Wg_out1);
    k_prepw<<<gW224, 256, 0, stream>>>(W_in2, 600, 400, 200, 224, 0, Wg_in2);
    k_prepw<<<gW224, 256, 0, stream>>>(W_out2, 600, 400, 200, 224, 0, Wg_out2);
    // relation combined weight [Wr | Wf] and bias br+bf
    k_prepwrf<<<gW448, 256, 0, stream>>>(Wr, Wf, Wrf_b);
    k_brf<<<1, 256, 0, stream>>>(br, bf, brf);

    // ---- CSR builds: by col (in), by row (out), by etype — with sorted payloads ----
    int nbN = (N + SCAN_CHUNK - 1) / SCAN_CHUNK;
    int nbM = (M + SCAN_CHUNK - 1) / SCAN_CHUNK;
    hipMemsetAsync(cnt, 0, (size_t)N * 4, stream);
    k_count<<<gE, 256, 0, stream>>>(col, cnt, E);
    k_blocksum<<<nbN, 256, 0, stream>>>(cnt, bsum, N);
    k_scanwrite<<<nbN, 256, 0, stream>>>(cnt, bsum, offs_in, cur, N, nbN);
    k_scatter3<<<gE, 256, 0, stream>>>(col, row, etype, cur, nbrS_in, etS_in, keyS_in, E);

    hipMemsetAsync(cnt, 0, (size_t)N * 4, stream);
    k_count<<<gE, 256, 0, stream>>>(row, cnt, E);
    k_blocksum<<<nbN, 256, 0, stream>>>(cnt, bsum, N);
    k_scanwrite<<<nbN, 256, 0, stream>>>(cnt, bsum, offs_out, cur, N, nbN);
    k_scatter3<<<gE, 256, 0, stream>>>(row, col, etype, cur, nbrS_out, etS_out, keyS_out, E);

    hipMemsetAsync(cnt, 0, (size_t)M * 4, stream);
    k_count<<<gE, 256, 0, stream>>>(etype, cnt, E);
    k_blocksum<<<nbM, 256, 0, stream>>>(cnt, bsum, M);
    k_scanwrite<<<nbM, 256, 0, stream>>>(cnt, bsum, offsT, cur, M, nbM);
    k_scatter2<<<gE, 256, 0, stream>>>(etype, cur, rsT, csT, row, col, E);

    // ---- hop 1 setup ----
    k_watt<<<(2 * 300 + 255) / 256, 256, 0, stream>>>(att_in1, W_in1, wa_in, 2, 100, 300);
    k_watt<<<(2 * 300 + 255) / 256, 256, 0, stream>>>(att_out1, W_out1, wa_out, 2, 100, 300);
    k_dots<false><<<gN4, 256, 0, stream>>>(x, invn, wa_in, rdot_in, cdot_in, N);
    k_dots<false><<<gN4, 256, 0, stream>>>(x, invn, wa_out, rdot_out, cdot_out, N);
    k_gdot<<<(M * 2 + 255) / 256, 256, 0, stream>>>(g, wa_in, gdot_in, M, 2, 100, 300);
    k_gdot<<<(M * 2 + 255) / 256, 256, 0, stream>>>(g, wa_out, gdot_out, M, 2, 100, 300);
    // pg via MFMA: bf16(g) into combo cols 0..127, then GEMM with W[:,200:300]
    k_gcb<<<((int)(((size_t)M * 128 + 255) / 256)), 256, 0, stream>>>(g, gcomb, M);
    k_mgemm<4, false, false, false><<<gM64, 256, 0, stream>>>(gcomb, Wg_in1, nullptr, nullptr, pg_in, M, 448);
    k_mgemm<4, false, false, false><<<gM64, 256, 0, stream>>>(gcomb, Wg_out1, nullptr, nullptr, pg_out, M, 448);
    k_ew_s<<<(E * 2 + 255) / 256, 256, 0, stream>>>(nbrS_in, keyS_in, etS_in, rdot_in, cdot_in, gdot_in, ewS_in, E, 2);
    k_ew_s<<<(E * 2 + 255) / 256, 256, 0, stream>>>(nbrS_out, keyS_out, etS_out, cdot_out, rdot_out, gdot_out, ewS_out, E, 2);

    for (int n0 = 0; n0 < N; n0 += C) {
        int rows = (N - n0 < C) ? (N - n0) : C;
        int n1 = n0 + rows;
        int ga = (rows + 3) / 4;
        int gb = (rows + 63) / 64;
        k_xcb<<<(rows * 128 + 255) / 256, 256, 0, stream>>>(x + (size_t)n0 * 100, invn + n0, sb, rows);
        // in-direction (ends=col, nbr=row)
        k_agg<2, false><<<ga, 256, 0, stream>>>(offs_in, nbrS_in, etS_in, ewS_in, pg_in, x, invn, agg_b, hbA, n0, n1);
        k_mgemm<4, false, true, true><<<gb, 256, 0, stream>>>(sb, Ws_in1, nullptr, offs_in + n0, hbA, rows, 128);
        k_mgemm<7, false, true, false><<<gb, 256, 0, stream>>>(agg_b, Wa_in1, nullptr, nullptr, hbA, rows, 224);
        // out-direction (ends=row, nbr=col)
        k_agg<2, false><<<ga, 256, 0, stream>>>(offs_out, nbrS_out, etS_out, ewS_out, pg_out, x, invn, agg_b, hbB, n0, n1);
        k_mgemm<4, false, true, true><<<gb, 256, 0, stream>>>(sb, Ws_out1, nullptr, offs_out + n0, hbB, rows, 128);
        k_mgemm<7, false, true, false><<<gb, 256, 0, stream>>>(agg_b, Wa_out1, nullptr, nullptr, hbB, rows, 224);
        // epilogues + merge GEMMs
        gat_post2<100, 2><<<(2 * rows + 3) / 4, 256, 0, stream>>>(hbA, post_b, 2 * rows);
        k_mgemm<7, true, false, false><<<gb, 256, 0, stream>>>(post_b, Wm_i1, bi1, nullptr, hbA, rows, 224);
        gat_post2<100, 2><<<(2 * rows + 3) / 4, 256, 0, stream>>>(hbB, post_b, 2 * rows);
        k_mgemm<7, true, false, false><<<gb, 256, 0, stream>>>(post_b, Wm_o1, bo1, nullptr, hbB, rows, 224);
        merge_comb<<<ga, 256, 0, stream>>>(hbA, hbB, Wl1, bl1, h1 + (size_t)n0 * 200, rows);
    }

    // ---- relation layer: block-per-type segment sum + one fused GEMM ----
    k_gedges_b<<<M, 256, 0, stream>>>(rsT, csT, offsT, x, invn, g, gcomb, M);
    k_mgemm<14, true, false, false><<<gM64, 256, 0, stream>>>(gcomb, Wrf_b, brf, nullptr, gp, M, 448);

    // ---- hop 2 setup ----
    k_watt<<<(600 + 255) / 256, 256, 0, stream>>>(att_in2, W_in2, wa_in, 1, 200, 600);
    k_watt<<<(600 + 255) / 256, 256, 0, stream>>>(att_out2, W_out2, wa_out, 1, 200, 600);
    k_dots<true><<<gN4, 256, 0, stream>>>(h1, nullptr, wa_in, rdot_in, cdot_in, N);
    k_dots<true><<<gN4, 256, 0, stream>>>(h1, nullptr, wa_out, rdot_out, cdot_out, N);
    k_gdot<<<(M + 255) / 256, 256, 0, stream>>>(gp, wa_in, gdot_in, M, 1, 200, 600);
    k_gdot<<<(M + 255) / 256, 256, 0, stream>>>(gp, wa_out, gdot_out, M, 1, 200, 600);
    // pg2 via MFMA: bf16(gp) reusing combo buffer as [M][224], GEMM with W[:,400:600]
    k_h1b<<<((int)(((size_t)M * 224 + 255) / 256)), 256, 0, stream>>>(gp, gcomb, M);
    k_mgemm<7, false, false, false><<<gM64, 256, 0, stream>>>(gcomb, Wg_in2, nullptr, nullptr, pg_in, M, 224);
    k_mgemm<7, false, false, false><<<gM64, 256, 0, stream>>>(gcomb, Wg_out2, nullptr, nullptr, pg_out, M, 224);
    k_ew_s<<<(E + 255) / 256, 256, 0, stream>>>(nbrS_in, keyS_in, etS_in, rdot_in, cdot_in, gdot_in, ewS_in, E, 1);
    k_ew_s<<<(E + 255) / 256, 256, 0, stream>>>(nbrS_out, keyS_out, etS_out, cdot_out, rdot_out, gdot_out, ewS_out, E, 1);

    for (int n0 = 0; n0 < N; n0 += C) {
        int rows = (N - n0 < C) ? (N - n0) : C;
        int n1 = n0 + rows;
        int ga = (rows + 3) / 4;
        int gb = (rows + 63) / 64;
        k_h1b<<<(rows * 224 + 255) / 256, 256, 0, stream>>>(h1 + (size_t)n0 * 200, sb, rows);
        k_agg<1, true><<<ga, 256, 0, stream>>>(offs_in, nbrS_in, etS_in, ewS_in, pg_in, h1, nullptr, agg_b, hbA, n0, n1);
        k_mgemm<7, false, true, true><<<gb, 256, 0, stream>>>(sb, Ws_in2, nullptr, offs_in + n0, hbA, rows, 224);
        k_mgemm<7, false, true, false><<<gb, 256, 0, stream>>>(agg_b, Wa_in2, nullptr, nullptr, hbA, rows, 224);
        k_agg<1, true><<<ga, 256, 0, stream>>>(offs_out, nbrS_out, etS_out, ewS_out, pg_out, h1, nullptr, agg_b, hbB, n0, n1);
        k_mgemm<7, false, true, true><<<gb, 256, 0, stream>>>(sb, Ws_out2, nullptr, offs_out + n0, hbB, rows, 224);
        k_mgemm<7, false, true, false><<<gb, 256, 0, stream>>>(agg_b, Wa_out2, nullptr, nullptr, hbB, rows, 224);
        gat_post2<200, 1><<<ga, 256, 0, stream>>>(hbA, post_b, rows);
        k_mgemm<7, true, false, false><<<gb, 256, 0, stream>>>(post_b, Wm_i2, bi2, nullptr, hbA, rows, 224);
        gat_post2<200, 1><<<ga, 256, 0, stream>>>(hbB, post_b, rows);
        k_mgemm<7, true, false, false><<<gb, 256, 0, stream>>>(post_b, Wm_o2, bo2, nullptr, hbB, rows, 224);
        merge_comb<<<ga, 256, 0, stream>>>(hbA, hbB, Wl2, bl2, out + (size_t)n0 * 200, rows);
        // entity residual for this chunk: out += l2norm(x) @ W_ent^T
        k_xcb<<<(rows * 128 + 255) / 256, 256, 0, stream>>>(x + (size_t)n0 * 100, invn + n0, sb, rows);
        k_mgemm<4, false, true, false><<<gb, 256, 0, stream>>>(sb, Wb_ent, nullptr, nullptr, out + (size_t)n0 * 200, rows, 128);
    }
}

// Round 3
// 2887.011 us; speedup vs baseline: 1.2511x; 1.0247x over previous
//
#include <hip/hip_runtime.h>
#include <cstddef>
#include <cstdint>

#define WSLOPE 0.2f
#define WEPS 1e-12f

typedef __attribute__((ext_vector_type(8))) short bf16x8;
typedef __attribute__((ext_vector_type(4))) float f32x4;

__device__ __forceinline__ float waveSum(float v) {
#pragma unroll
    for (int off = 32; off > 0; off >>= 1) v += __shfl_xor(v, off, 64);
    return v;
}
__device__ __forceinline__ float eluf(float v) { return v > 0.f ? v : expm1f(v); }
__device__ __forceinline__ short f2bf(float f) {
    union { float f; uint32_t u; } v; v.f = f;
    uint32_t r = v.u + 0x7FFF + ((v.u >> 16) & 1);
    return (short)(r >> 16);
}
__device__ __forceinline__ float bf2f(short s) {
    union { uint32_t u; float f; } v; v.u = ((uint32_t)(uint16_t)s) << 16;
    return v.f;
}

// ---------------- per-node inverse L2 norm of x ----------------
__global__ void k_invnorm(const float* __restrict__ x, float* __restrict__ invn, int N) {
    int wid = blockIdx.x * 4 + (threadIdx.x >> 6);
    int lane = threadIdx.x & 63;
    if (wid >= N) return;
    const float* p = x + (size_t)wid * 100;
    float a = p[lane];
    float ss = a * a;
    if (lane < 36) { float b = p[lane + 64]; ss += b * b; }
    ss = waveSum(ss);
    if (lane == 0) invn[wid] = 1.f / fmaxf(sqrtf(ss), WEPS);
}

// ---------------- generic CSR build (counting sort) ----------------
__global__ void k_count(const int* __restrict__ keys, int* __restrict__ cnt, int n) {
    int i = blockIdx.x * 256 + threadIdx.x;
    if (i < n) atomicAdd(&cnt[keys[i]], 1);
}

#define SCAN_CHUNK 2048
__global__ void k_blocksum(const int* __restrict__ cnt, int* __restrict__ bsum, int n) {
    __shared__ int sh[256];
    int b = blockIdx.x, t = threadIdx.x;
    int base = b * SCAN_CHUNK;
    int s = 0;
    for (int i = t; i < SCAN_CHUNK; i += 256) { int idx = base + i; if (idx < n) s += cnt[idx]; }
    sh[t] = s; __syncthreads();
    for (int off = 128; off > 0; off >>= 1) { if (t < off) sh[t] += sh[t + off]; __syncthreads(); }
    if (t == 0) bsum[b] = sh[0];
}

__global__ void k_scanwrite(const int* __restrict__ cnt, const int* __restrict__ bsum,
                            int* __restrict__ offs, int* __restrict__ cur, int n, int nb) {
    __shared__ int sh[256];
    __shared__ int sbase;
    int b = blockIdx.x, t = threadIdx.x;
    if (t == 0) { int s = 0; for (int i = 0; i < b; ++i) s += bsum[i]; sbase = s; }
    __syncthreads();
    int base = b * SCAN_CHUNK;
    int loc[8]; int ts = 0;
#pragma unroll
    for (int i = 0; i < 8; ++i) { int idx = base + t * 8 + i; int v = (idx < n) ? cnt[idx] : 0; loc[i] = ts; ts += v; }
    sh[t] = ts; __syncthreads();
    for (int off = 1; off < 256; off <<= 1) {
        int v = (t >= off) ? sh[t - off] : 0;
        __syncthreads();
        sh[t] += v;
        __syncthreads();
    }
    int excl = (t == 0) ? 0 : sh[t - 1];
    int gbase = sbase + excl;
#pragma unroll
    for (int i = 0; i < 8; ++i) {
        int idx = base + t * 8 + i;
        if (idx < n) { offs[idx] = gbase + loc[i]; cur[idx] = gbase + loc[i]; }
    }
    if (b == nb - 1 && t == 255) offs[n] = sbase + sh[255];
}

// scatter with payload: sorted neighbor / etype / key arrays
__global__ void k_scatter3(const int* __restrict__ keys, const int* __restrict__ other,
                           const int* __restrict__ et, int* __restrict__ cur,
                           int* __restrict__ nbrS, int* __restrict__ etS,
                           int* __restrict__ keyS, int n) {
    int i = blockIdx.x * 256 + threadIdx.x;
    if (i < n) {
        int p = atomicAdd(&cur[keys[i]], 1);
        nbrS[p] = other[i];
        etS[p] = et[i];
        keyS[p] = keys[i];
    }
}

// scatter for etype sort: store both endpoints in sorted order
__global__ void k_scatter2(const int* __restrict__ keys, int* __restrict__ cur,
                           int* __restrict__ rs, int* __restrict__ cs,
                           const int* __restrict__ row, const int* __restrict__ col, int n) {
    int i = blockIdx.x * 256 + threadIdx.x;
    if (i < n) {
        int p = atomicAdd(&cur[keys[i]], 1);
        rs[p] = row[i];
        cs[p] = col[i];
    }
}

// ---------------- attention vector ----------------
__global__ void k_watt(const float* __restrict__ att, const float* __restrict__ W,
                       float* __restrict__ wa, int H, int DH, int K) {
    int id = blockIdx.x * 256 + threadIdx.x;
    if (id >= H * K) return;
    int h = id / K, k = id % K;
    float s = 0.f;
    for (int j = 0; j < DH; ++j) s += att[h * DH + j] * W[(size_t)(h * DH + j) * K + k];
    wa[id] = s;
}

// ---------------- per-node partial dots ----------------
template<bool HOP2>
__global__ void k_dots(const float* __restrict__ feat, const float* __restrict__ invn,
                       const float* __restrict__ wa, float* __restrict__ rdot,
                       float* __restrict__ cdot, int N) {
    int wid = blockIdx.x * 4 + (threadIdx.x >> 6);
    int lane = threadIdx.x & 63;
    if (wid >= N) return;
    if (!HOP2) {
        float inv = invn[wid];
        const float* p = feat + (size_t)wid * 100;
        float f0 = p[lane] * inv;
        float f1 = (lane < 36) ? p[lane + 64] * inv : 0.f;
#pragma unroll
        for (int h = 0; h < 2; ++h) {
            const float* w = wa + h * 300;
            float r = f0 * w[lane] + ((lane < 36) ? f1 * w[lane + 64] : 0.f);
            float c = f0 * w[100 + lane] + ((lane < 36) ? f1 * w[100 + lane + 64] : 0.f);
            r = waveSum(r); c = waveSum(c);
            if (lane == 0) { rdot[wid * 2 + h] = r; cdot[wid * 2 + h] = c; }
        }
    } else {
        const float* p = feat + (size_t)wid * 200;
        float r = 0.f, c = 0.f;
#pragma unroll
        for (int m = 0; m < 4; ++m) {
            int d = lane + m * 64;
            if (d < 200) { float f = p[d]; r += f * wa[d]; c += f * wa[200 + d]; }
        }
        r = waveSum(r); c = waveSum(c);
        if (lane == 0) { rdot[wid] = r; cdot[wid] = c; }
    }
}

// ---------------- per-type dot ----------------
__global__ void k_gdot(const float* __restrict__ gsrc, const float* __restrict__ wa,
                       float* __restrict__ gdot, int M, int H, int GL, int K) {
    int id = blockIdx.x * 256 + threadIdx.x;
    if (id >= M * H) return;
    int m = id / H, h = id % H;
    float s = 0.f;
    const float* w = wa + h * K + 2 * GL;
    const float* gm = gsrc + (size_t)m * GL;
    for (int kk = 0; kk < GL; ++kk) s += gm[kk] * w[kk];
    gdot[id] = s;
}

// ---------------- per-edge weight, written in CSR-sorted order ----------------
__global__ void k_ew_s(const int* __restrict__ nbrS, const int* __restrict__ keyS,
                       const int* __restrict__ etS,
                       const float* __restrict__ ndot, const float* __restrict__ kdot,
                       const float* __restrict__ gdot, float* __restrict__ ewS, int E, int H) {
    int id = blockIdx.x * 256 + threadIdx.x;
    if (id >= E * H) return;
    int p = id / H, h = id - p * H;
    float a = ndot[nbrS[p] * H + h] + kdot[keyS[p] * H + h] + gdot[etS[p] * H + h];
    float lr = a > 0.f ? a : WSLOPE * a;
    ewS[id] = expf(-lr);
}

// ---------------- CSR aggregation: wave per node, bf16 gathers, combined A-row ----------------
// HOP1: A row [576] = [agg 224 blockdiag | z0 112 | z1 112 | self 128]
// HOP2: A row [672] = [agg 224           | z 224            | self 224]
template<bool HOP2>
__global__ void k_agg(const int* __restrict__ offs, const int* __restrict__ nbrS,
                      const int* __restrict__ etS, const float* __restrict__ ewS,
                      const short* __restrict__ featB, const short* __restrict__ gB,
                      short* __restrict__ A, int n0, int n1) {
    constexpr int H = HOP2 ? 1 : 2;
    constexpr int LDA = HOP2 ? 672 : 576;
    constexpr int FW = HOP2 ? 224 : 112;
    constexpr int GW = HOP2 ? 224 : 112;
    int node = n0 + blockIdx.x * 4 + (threadIdx.x >> 6);
    int lane = threadIdx.x & 63;
    if (node >= n1) return;
    int o = offs[node];
    int deg = offs[node + 1] - o;
    float va[7];
#pragma unroll
    for (int m = 0; m < 7; ++m) va[m] = 0.f;
    if (deg > 0) {
        float s0 = 0.f, s1 = 0.f;
        for (int i = lane; i < deg; i += 64) {
            s0 += ewS[(size_t)(o + i) * H];
            if (H == 2) s1 += ewS[(size_t)(o + i) * H + 1];
        }
        s0 = waveSum(s0);
        float rd0 = 1.f / s0, rd1 = rd0;
        if (H == 2) { s1 = waveSum(s1); rd1 = 1.f / s1; }
        for (int j = 0; j < deg; ++j) {
            float a0 = ewS[(size_t)(o + j) * H] * rd0;
            float a1 = (H == 2) ? ewS[(size_t)(o + j) * H + 1] * rd1 : a0;
            int nbr = nbrS[o + j];
            int et = etS[o + j];
            const short* fr = featB + (size_t)nbr * FW;
            const short* gr = gB + (size_t)et * GW;
            if (!HOP2) {
#pragma unroll
                for (int m = 0; m < 7; ++m) {
                    int d = lane + m * 64;
                    if (d < 100) va[m] += a0 * bf2f(fr[d]);
                    else if (d < 200) va[m] += a1 * bf2f(fr[d - 100]);
                    else if (d < 300) va[m] += a0 * bf2f(gr[d - 200]);
                    else if (d < 400) va[m] += a1 * bf2f(gr[d - 300]);
                }
            } else {
#pragma unroll
                for (int m = 0; m < 7; ++m) {
                    int d = lane + m * 64;
                    if (d < 200) va[m] += a0 * bf2f(fr[d]);
                    else if (d < 424) va[m] += a0 * bf2f(gr[d - 200]);
                }
            }
        }
    }
    size_t rb = (size_t)(node - n0);
    short* Ar = A + rb * LDA;
    if (!HOP2) {
#pragma unroll
        for (int m = 0; m < 7; ++m) {
            int d = lane + m * 64;
            if (d < 400) {
                int col = d < 100 ? d : (d < 200 ? d + 12 : (d < 300 ? d + 24 : d + 36));
                Ar[col] = f2bf(va[m]);
            }
        }
        // pads: 100..111, 212..223, 324..335, 436..447
        if (lane < 48) { int q = lane / 12; int rm = lane - q * 12; Ar[q * 112 + 100 + rm] = 0; }
        // self copy (masked): cols 448..575
        const short* sf = featB + (size_t)node * 112;
#pragma unroll
        for (int mm = 0; mm < 2; ++mm) {
            int k = lane + mm * 64;
            if (k < 128) Ar[448 + k] = (deg > 0 && k < 112) ? sf[k] : (short)0;
        }
    } else {
#pragma unroll
        for (int m = 0; m < 7; ++m) {
            int d = lane + m * 64;
            if (d < 424) Ar[d < 200 ? d : d + 24] = f2bf(va[m]);
        }
        if (lane < 24) Ar[200 + lane] = 0;
        const short* sf = featB + (size_t)node * 224;
#pragma unroll
        for (int mm = 0; mm < 4; ++mm) {
            int k = lane + mm * 64;
            if (k < 224) Ar[448 + k] = deg > 0 ? sf[k] : (short)0;
        }
    }
}

// ---------------- bf16 MFMA GEMM: out[r][0..199] (+)= A_bf16[r][lda] @ Wb[208][K]^T ----------------
template<int KSTEPS, bool BIAS, bool ACC>
__launch_bounds__(256)
__global__ void k_mgemm(const short* __restrict__ A, const short* __restrict__ Wb,
                        const float* __restrict__ bias,
                        float* __restrict__ out, int rows, int lda) {
    constexpr int LDW = KSTEPS * 32;
    const int t = threadIdx.x;
    const int wv = t >> 6, l = t & 63;
    const int lhi = l >> 4, llo = l & 15;
    const int rbase = blockIdx.x * 64 + wv * 16;
    f32x4 acc[13];
#pragma unroll
    for (int j = 0; j < 13; ++j) acc[j] = f32x4{0.f, 0.f, 0.f, 0.f};
    const short* arow = A + (size_t)(rbase + llo) * lda + lhi * 8;
#pragma unroll
    for (int kt = 0; kt < KSTEPS; ++kt) {
        bf16x8 a = *(const bf16x8*)(arow + kt * 32);
#pragma unroll
        for (int j = 0; j < 13; ++j) {
            bf16x8 b = *(const bf16x8*)(Wb + (size_t)(j * 16 + llo) * LDW + kt * 32 + lhi * 8);
            acc[j] = __builtin_amdgcn_mfma_f32_16x16x32_bf16(a, b, acc[j], 0, 0, 0);
        }
    }
    const int r0 = rbase + lhi * 4;
#pragma unroll
    for (int e = 0; e < 4; ++e) {
        int r = r0 + e;
        if (r >= rows) continue;
        float* orow = out + (size_t)r * 200;
#pragma unroll
        for (int j = 0; j < 13; ++j) {
            int d = j * 16 + llo;
            if (d < 200) {
                float v = acc[j][e];
                if (BIAS) v += bias[d];
                if (ACC) v += orow[d];
                orow[d] = v;
            }
        }
    }
}

// ---------------- weight prep: f32 -> bf16 region [208][span] at dst within [208][ldWb] ----------------
// mode 0: Wb[d][dst+k] = W[d][koff+k] for k<Klen
// mode 1 (block-diag per head): h=d/100; Wb[d][dst+h*112+kk] = W[d][koff+kk], kk<Klen
__global__ void k_prepw(const float* __restrict__ W, int ldW, int koff, int Klen, int span,
                        int mode, short* __restrict__ Wb, int ldWb, int dst) {
    int id = blockIdx.x * 256 + threadIdx.x;
    int tot = 208 * span;
    if (id >= tot) return;
    int d = id / span, k = id - d * span;
    float v = 0.f;
    if (d < 200) {
        if (mode == 0) { if (k < Klen) v = W[(size_t)d * ldW + koff + k]; }
        else { int h = d / 100; int kk = k - h * 112; if (kk >= 0 && kk < Klen) v = W[(size_t)d * ldW + koff + kk]; }
    }
    Wb[(size_t)d * ldWb + dst + k] = f2bf(v);
}

// combined [Wr | 0pad | Wf] -> bf16 [208][448]  (cols 0..99 = Wr, 128..427 = Wf)
__global__ void k_prepwrf(const float* __restrict__ Wr, const float* __restrict__ Wf,
                          short* __restrict__ Wb) {
    int id = blockIdx.x * 256 + threadIdx.x;
    if (id >= 208 * 448) return;
    int d = id / 448, k = id - d * 448;
    float v = 0.f;
    if (d < 200) {
        if (k < 100) v = Wr[(size_t)d * 100 + k];
        else if (k >= 128 && k < 428) v = Wf[(size_t)d * 300 + (k - 128)];
    }
    Wb[id] = f2bf(v);
}

__global__ void k_brf(const float* __restrict__ br, const float* __restrict__ bf,
                      float* __restrict__ brf) {
    int d = threadIdx.x;
    if (d < 200) brf[d] = br[d] + bf[d];
}

// ---------------- converts ----------------
// src [rows][100] f32 (optionally *invn[r]) -> bf16 [rows][112] (cols 100..111 = 0)
__global__ void k_cvt112(const float* __restrict__ src, const float* __restrict__ invn,
                         short* __restrict__ dst, int rows) {
    int id = blockIdx.x * 256 + threadIdx.x;
    if (id >= rows * 112) return;
    int r = id / 112, k = id - r * 112;
    float v = 0.f;
    if (k < 100) { v = src[(size_t)r * 100 + k]; if (invn) v *= invn[r]; }
    dst[id] = f2bf(v);
}

// g [rows][100] f32 -> bf16 into combo buffer cols 0..127 (row stride 448)
__global__ void k_gcb(const float* __restrict__ g, short* __restrict__ gb, int rows) {
    int id = blockIdx.x * 256 + threadIdx.x;
    if (id >= rows * 128) return;
    int r = id >> 7, k = id & 127;
    gb[(size_t)r * 448 + k] = f2bf(k < 100 ? g[(size_t)r * 100 + k] : 0.f);
}

// src [rows][200] f32 -> bf16 [rows][224] (cols 200..223 = 0)
__global__ void k_h1b(const float* __restrict__ h1, short* __restrict__ sb, int rows) {
    int id = blockIdx.x * 256 + threadIdx.x;
    if (id >= rows * 224) return;
    int r = id / 224, k = id - r * 224;
    sb[id] = f2bf(k < 200 ? h1[(size_t)r * 200 + k] : 0.f);
}

// ---------------- GAT epilogue: elu + per-(node,head) l2norm -> bf16 padded ----------------
template<int DH, int H>
__global__ void gat_post2(const float* __restrict__ hb, short* __restrict__ pb, int rowsH) {
    int nh = blockIdx.x * 4 + (threadIdx.x >> 6);
    int lane = threadIdx.x & 63;
    if (nh >= rowsH) return;
    const float* p = hb + (size_t)nh * DH;
    constexpr int MM = (DH + 63) / 64;
    float v[MM];
    float ss = 0.f;
#pragma unroll
    for (int m = 0; m < MM; ++m) {
        int d = lane + m * 64;
        v[m] = 0.f;
        if (d < DH) { v[m] = eluf(p[d]); ss += v[m] * v[m]; }
    }
    ss = waveSum(ss);
    float inv = 1.f / fmaxf(sqrtf(ss), WEPS);
    short* ob = pb + (size_t)(nh / H) * 224 + (size_t)(nh % H) * DH;
#pragma unroll
    for (int m = 0; m < MM; ++m) {
        int d = lane + m * 64;
        if (d < DH) ob[d] = f2bf(v[m] * inv);
    }
}

// ---------------- merge combine (optionally also emits bf16 copy [*,224]) ----------------
__global__ void merge_comb(const float* __restrict__ hi, const float* __restrict__ ho,
                           const float* __restrict__ Wl, const float* __restrict__ bl,
                           float* __restrict__ out, short* __restrict__ hbf, int N) {
    int wid = blockIdx.x * 4 + (threadIdx.x >> 6);
    int lane = threadIdx.x & 63;
    if (wid >= N) return;
    float vi[4], vo[4];
    float s = 0.f;
#pragma unroll
    for (int m = 0; m < 4; ++m) {
        int d = lane + m * 64;
        vi[m] = 0.f; vo[m] = 0.f;
        if (d < 200) {
            vi[m] = hi[(size_t)wid * 200 + d];
            vo[m] = ho[(size_t)wid * 200 + d];
            s += Wl[d] * vi[m] + Wl[200 + d] * vo[m];
        }
    }
    s = waveSum(s);
    float lam = 1.f / (1.f + expf(-(s + bl[0])));
    float hv[4];
    float ss = 0.f;
#pragma unroll
    for (int m = 0; m < 4; ++m) {
        int d = lane + m * 64;
        hv[m] = 0.f;
        if (d < 200) {
            float h = lam * vi[m] + (1.f - lam) * vo[m];
            hv[m] = eluf(h);
            ss += hv[m] * hv[m];
        }
    }
    ss = waveSum(ss);
    float inv = 1.f / fmaxf(sqrtf(ss), WEPS);
#pragma unroll
    for (int m = 0; m < 4; ++m) {
        int d = lane + m * 64;
        if (d < 200) {
            float v = hv[m] * inv;
            out[(size_t)wid * 200 + d] = v;
            if (hbf) hbf[(size_t)wid * 224 + d] = f2bf(v);
        } else if (d < 224) {
            if (hbf) hbf[(size_t)wid * 224 + d] = 0;
        }
    }
}

// ---------------- relation layer: block per type, 384 threads, no divergent waves ----------------
// waves 0-1: row gather (dims 0..99); waves 2-3: col gather; waves 4-5: deg*g (off edge chain)
__global__ void k_gedges_b(const int* __restrict__ rsT, const int* __restrict__ csT,
                           const int* __restrict__ offsT,
                           const float* __restrict__ x, const float* __restrict__ invn,
                           const float* __restrict__ g, short* __restrict__ gcomb, int M) {
    __shared__ float red[6];
    int m = blockIdx.x, t = threadIdx.x;
    int o = offsT[m];
    int deg = offsT[m + 1] - o;
    float acc = 0.f;
    if (t < 128) {
        int d = t; bool ok = d < 100;
        for (int i = 0; i < deg; ++i) {
            int r = rsT[o + i];
            if (ok) acc += x[(size_t)r * 100 + d] * invn[r];
        }
    } else if (t < 256) {
        int d = t - 128; bool ok = d < 100;
        for (int i = 0; i < deg; ++i) {
            int c = csT[o + i];
            if (ok) acc += x[(size_t)c * 100 + d] * invn[c];
        }
    } else {
        int d = t - 256;
        if (d < 100) acc = (float)deg * g[(size_t)m * 100 + d];
    }
    float sq = waveSum(acc * acc);
    if ((t & 63) == 0) red[t >> 6] = sq;
    __syncthreads();
    float s2 = red[0] + red[1] + red[2] + red[3] + red[4] + red[5];
    float inv = 1.f / fmaxf(sqrtf(s2), WEPS);
    short* orow = gcomb + (size_t)m * 448 + 128;
    if (t < 128) {
        if (t < 100) orow[t] = f2bf(eluf(acc * inv));
    } else if (t < 256) {
        int d = t - 128;
        if (d < 100) orow[100 + d] = f2bf(eluf(acc * inv));
    } else {
        int d = t - 256;
        if (d < 100) orow[200 + d] = f2bf(eluf(acc * inv));
        else if (d < 120) orow[200 + d] = 0;   // pad cols 300..319
    }
}

// ---------------- host launch ----------------
extern "C" void kernel_launch(void* const* d_in, const int* in_sizes, int n_in,
                              void* d_out, int out_size, void* d_ws, size_t ws_size,
                              hipStream_t stream) {
    const int* eidx   = (const int*)d_in[0];
    const int* etype  = (const int*)d_in[1];
    const float* x    = (const float*)d_in[5];
    const float* g    = (const float*)d_in[6];
    const float* W_in1  = (const float*)d_in[7];
    const float* att_in1 = (const float*)d_in[8];
    const float* W_out1 = (const float*)d_in[9];
    const float* att_out1 = (const float*)d_in[10];
    const float* Wi1 = (const float*)d_in[11]; const float* bi1 = (const float*)d_in[12];
    const float* Wo1 = (const float*)d_in[13]; const float* bo1 = (const float*)d_in[14];
    const float* Wl1 = (const float*)d_in[15]; const float* bl1 = (const float*)d_in[16];
    const float* Wr  = (const float*)d_in[17]; const float* br  = (const float*)d_in[18];
    const float* Wf  = (const float*)d_in[19]; const float* bf  = (const float*)d_in[20];
    const float* W_in2  = (const float*)d_in[21]; const float* att_in2 = (const float*)d_in[22];
    const float* W_out2 = (const float*)d_in[23]; const float* att_out2 = (const float*)d_in[24];
    const float* Wi2 = (const float*)d_in[25]; const float* bi2 = (const float*)d_in[26];
    const float* Wo2 = (const float*)d_in[27]; const float* bo2 = (const float*)d_in[28];
    const float* Wl2 = (const float*)d_in[29]; const float* bl2 = (const float*)d_in[30];
    const float* W_ent = (const float*)d_in[31];

    const int E = in_sizes[1];
    const int N = in_sizes[5] / 100;
    const int M = in_sizes[6] / 100;
    const int Mr = (M + 63) & ~63;
    float* out = (float*)d_out;
    const int* row = eidx;
    const int* col = eidx + E;

    char* w = (char*)d_ws;
    size_t off_b = 0;
    auto alloc = [&](size_t bytes) -> void* {
        void* p = w + off_b;
        off_b += (bytes + 255) & ~(size_t)255;
        return p;
    };
    float* invn  = (float*)alloc((size_t)N * 4);
    float* h1    = (float*)alloc((size_t)N * 200 * 4);
    short* h1_bf = (short*)alloc((size_t)(N + 64) * 224 * 2);
    short* xn_bf = (short*)alloc((size_t)(N + 64) * 112 * 2);
    short* g_bf  = (short*)alloc((size_t)M * 112 * 2);
    int* offs_in = (int*)alloc((size_t)(N + 1) * 4);
    int* offs_out= (int*)alloc((size_t)(N + 1) * 4);
    int* offsT   = (int*)alloc((size_t)(M + 1) * 4);
    int* nbrS_in = (int*)alloc((size_t)E * 4);
    int* etS_in  = (int*)alloc((size_t)E * 4);
    int* keyS_in = (int*)alloc((size_t)E * 4);
    int* nbrS_out= (int*)alloc((size_t)E * 4);
    int* etS_out = (int*)alloc((size_t)E * 4);
    int* keyS_out= (int*)alloc((size_t)E * 4);
    int* rsT     = (int*)alloc((size_t)E * 4);
    int* csT     = (int*)alloc((size_t)E * 4);
    int* cnt     = (int*)alloc((size_t)N * 4);
    int* cur     = (int*)alloc((size_t)N * 4);
    int* bsum    = (int*)alloc((size_t)64 * 4);
    float* wa_in = (float*)alloc((size_t)1200 * 4);
    float* wa_out= (float*)alloc((size_t)1200 * 4);
    float* rdot_in = (float*)alloc((size_t)N * 2 * 4);
    float* cdot_in = (float*)alloc((size_t)N * 2 * 4);
    float* rdot_out= (float*)alloc((size_t)N * 2 * 4);
    float* cdot_out= (float*)alloc((size_t)N * 2 * 4);
    float* gdot_in = (float*)alloc((size_t)M * 2 * 4);
    float* gdot_out= (float*)alloc((size_t)M * 2 * 4);
    float* ewS_in  = (float*)alloc((size_t)E * 2 * 4);
    float* ewS_out = (float*)alloc((size_t)E * 2 * 4);
    float* gp      = (float*)alloc((size_t)M * 200 * 4);
    // combo bf16 buffer: relation [Mr][448] (cols 0..127 g, 128..447 ge_n); hop2 reuse as gp bf16 [M][224]
    short* gcomb   = (short*)alloc((size_t)Mr * 448 * 2);
    // bf16 weight buffers
    short* Wc_in1  = (short*)alloc((size_t)208 * 576 * 2);
    short* Wc_out1 = (short*)alloc((size_t)208 * 576 * 2);
    short* Wc_in2  = (short*)alloc((size_t)208 * 672 * 2);
    short* Wc_out2 = (short*)alloc((size_t)208 * 672 * 2);
    short* Wm_i1   = (short*)alloc((size_t)208 * 224 * 2);
    short* Wm_o1   = (short*)alloc((size_t)208 * 224 * 2);
    short* Wm_i2   = (short*)alloc((size_t)208 * 224 * 2);
    short* Wm_o2   = (short*)alloc((size_t)208 * 224 * 2);
    short* Wb_ent  = (short*)alloc((size_t)208 * 128 * 2);
    short* Wrf_b   = (short*)alloc((size_t)208 * 448 * 2);
    float* brf     = (float*)alloc((size_t)200 * 4);

    // chunk buffers: per-row 800(hbA) + 800(hbB) + 1344(Ac) + 448(post_b) = 3392 B
    if (off_b >= ws_size) return;
    size_t rem = ws_size - off_b;
    long long Cll = (long long)(rem / 3520);
    long long Nr64 = ((long long)N + 63) & ~63LL;
    int C = (int)(Cll > Nr64 ? Nr64 : Cll);
    C &= ~63;
    if (C < 64) return;
    float* hbA   = (float*)alloc((size_t)C * 200 * 4);
    float* hbB   = (float*)alloc((size_t)C * 200 * 4);
    short* Ac    = (short*)alloc((size_t)C * 672 * 2);
    short* post_b= (short*)alloc((size_t)C * 224 * 2);
    if (off_b > ws_size) return;

    const int gE = (E + 255) / 256;
    const int gN4 = (N + 3) / 4;
    const int gM64 = (M + 63) / 64;

    k_invnorm<<<gN4, 256, 0, stream>>>(x, invn, N);

    // zero pad region of post_b once (gat_post2 never writes k>=200)
    hipMemsetAsync(post_b, 0, (size_t)C * 224 * 2, stream);

    // ---- bf16 feature tables ----
    k_cvt112<<<((int)(((size_t)N * 112 + 255) / 256)), 256, 0, stream>>>(x, invn, xn_bf, N);
    k_cvt112<<<((int)(((size_t)M * 112 + 255) / 256)), 256, 0, stream>>>(g, nullptr, g_bf, M);

    // ---- weight prep ----
    auto gsp = [](int span) { return (208 * span + 255) / 256; };
    // hop1 combined: [Wa(blockdiag nbr) | Wg(blockdiag) | Ws(self)]
    k_prepw<<<gsp(224), 256, 0, stream>>>(W_in1, 300, 0, 100, 224, 1, Wc_in1, 576, 0);
    k_prepw<<<gsp(224), 256, 0, stream>>>(W_in1, 300, 200, 100, 224, 1, Wc_in1, 576, 224);
    k_prepw<<<gsp(128), 256, 0, stream>>>(W_in1, 300, 100, 100, 128, 0, Wc_in1, 576, 448);
    k_prepw<<<gsp(224), 256, 0, stream>>>(W_out1, 300, 100, 100, 224, 1, Wc_out1, 576, 0);
    k_prepw<<<gsp(224), 256, 0, stream>>>(W_out1, 300, 200, 100, 224, 1, Wc_out1, 576, 224);
    k_prepw<<<gsp(128), 256, 0, stream>>>(W_out1, 300, 0, 100, 128, 0, Wc_out1, 576, 448);
    // hop2 combined: [Wa(nbr) | Wg | Ws(self)]
    k_prepw<<<gsp(224), 256, 0, stream>>>(W_in2, 600, 0, 200, 224, 0, Wc_in2, 672, 0);
    k_prepw<<<gsp(224), 256, 0, stream>>>(W_in2, 600, 400, 200, 224, 0, Wc_in2, 672, 224);
    k_prepw<<<gsp(224), 256, 0, stream>>>(W_in2, 600, 200, 200, 224, 0, Wc_in2, 672, 448);
    k_prepw<<<gsp(224), 256, 0, stream>>>(W_out2, 600, 200, 200, 224, 0, Wc_out2, 672, 0);
    k_prepw<<<gsp(224), 256, 0, stream>>>(W_out2, 600, 400, 200, 224, 0, Wc_out2, 672, 224);
    k_prepw<<<gsp(224), 256, 0, stream>>>(W_out2, 600, 0, 200, 224, 0, Wc_out2, 672, 448);
    // merge weights
    k_prepw<<<gsp(224), 256, 0, stream>>>(Wi1, 200, 0, 200, 224, 0, Wm_i1, 224, 0);
    k_prepw<<<gsp(224), 256, 0, stream>>>(Wo1, 200, 0, 200, 224, 0, Wm_o1, 224, 0);
    k_prepw<<<gsp(224), 256, 0, stream>>>(Wi2, 200, 0, 200, 224, 0, Wm_i2, 224, 0);
    k_prepw<<<gsp(224), 256, 0, stream>>>(Wo2, 200, 0, 200, 224, 0, Wm_o2, 224, 0);
    k_prepw<<<gsp(128), 256, 0, stream>>>(W_ent, 100, 0, 100, 128, 0, Wb_ent, 128, 0);
    // relation combined weight [Wr | Wf] and bias br+bf
    k_prepwrf<<<gsp(448), 256, 0, stream>>>(Wr, Wf, Wrf_b);
    k_brf<<<1, 256, 0, stream>>>(br, bf, brf);

    // ---- CSR builds with sorted payloads ----
    int nbN = (N + SCAN_CHUNK - 1) / SCAN_CHUNK;
    int nbM = (M + SCAN_CHUNK - 1) / SCAN_CHUNK;
    hipMemsetAsync(cnt, 0, (size_t)N * 4, stream);
    k_count<<<gE, 256, 0, stream>>>(col, cnt, E);
    k_blocksum<<<nbN, 256, 0, stream>>>(cnt, bsum, N);
    k_scanwrite<<<nbN, 256, 0, stream>>>(cnt, bsum, offs_in, cur, N, nbN);
    k_scatter3<<<gE, 256, 0, stream>>>(col, row, etype, cur, nbrS_in, etS_in, keyS_in, E);

    hipMemsetAsync(cnt, 0, (size_t)N * 4, stream);
    k_count<<<gE, 256, 0, stream>>>(row, cnt, E);
    k_blocksum<<<nbN, 256, 0, stream>>>(cnt, bsum, N);
    k_scanwrite<<<nbN, 256, 0, stream>>>(cnt, bsum, offs_out, cur, N, nbN);
    k_scatter3<<<gE, 256, 0, stream>>>(row, col, etype, cur, nbrS_out, etS_out, keyS_out, E);

    hipMemsetAsync(cnt, 0, (size_t)M * 4, stream);
    k_count<<<gE, 256, 0, stream>>>(etype, cnt, E);
    k_blocksum<<<nbM, 256, 0, stream>>>(cnt, bsum, M);
    k_scanwrite<<<nbM, 256, 0, stream>>>(cnt, bsum, offsT, cur, M, nbM);
    k_scatter2<<<gE, 256, 0, stream>>>(etype, cur, rsT, csT, row, col, E);

    // ---- hop 1 setup ----
    k_watt<<<(2 * 300 + 255) / 256, 256, 0, stream>>>(att_in1, W_in1, wa_in, 2, 100, 300);
    k_watt<<<(2 * 300 + 255) / 256, 256, 0, stream>>>(att_out1, W_out1, wa_out, 2, 100, 300);
    k_dots<false><<<gN4, 256, 0, stream>>>(x, invn, wa_in, rdot_in, cdot_in, N);
    k_dots<false><<<gN4, 256, 0, stream>>>(x, invn, wa_out, rdot_out, cdot_out, N);
    k_gdot<<<(M * 2 + 255) / 256, 256, 0, stream>>>(g, wa_in, gdot_in, M, 2, 100, 300);
    k_gdot<<<(M * 2 + 255) / 256, 256, 0, stream>>>(g, wa_out, gdot_out, M, 2, 100, 300);
    k_ew_s<<<(E * 2 + 255) / 256, 256, 0, stream>>>(nbrS_in, keyS_in, etS_in, rdot_in, cdot_in, gdot_in, ewS_in, E, 2);
    k_ew_s<<<(E * 2 + 255) / 256, 256, 0, stream>>>(nbrS_out, keyS_out, etS_out, cdot_out, rdot_out, gdot_out, ewS_out, E, 2);
    // relation-layer g bf16 (cols 0..127 of gcomb448)
    k_gcb<<<((int)(((size_t)M * 128 + 255) / 256)), 256, 0, stream>>>(g, gcomb, M);

    for (int n0 = 0; n0 < N; n0 += C) {
        int rows = (N - n0 < C) ? (N - n0) : C;
        int n1 = n0 + rows;
        int ga = (rows + 3) / 4;
        int gb = (rows + 63) / 64;
        // in-direction (ends=col, nbr=row, self=col)
        k_agg<false><<<ga, 256, 0, stream>>>(offs_in, nbrS_in, etS_in, ewS_in, xn_bf, g_bf, Ac, n0, n1);
        k_mgemm<18, false, false><<<gb, 256, 0, stream>>>(Ac, Wc_in1, nullptr, hbA, rows, 576);
        gat_post2<100, 2><<<(2 * rows + 3) / 4, 256, 0, stream>>>(hbA, post_b, 2 * rows);
        k_mgemm<7, true, false><<<gb, 256, 0, stream>>>(post_b, Wm_i1, bi1, hbA, rows, 224);
        // out-direction (ends=row, nbr=col, self=row)
        k_agg<false><<<ga, 256, 0, stream>>>(offs_out, nbrS_out, etS_out, ewS_out, xn_bf, g_bf, Ac, n0, n1);
        k_mgemm<18, false, false><<<gb, 256, 0, stream>>>(Ac, Wc_out1, nullptr, hbB, rows, 576);
        gat_post2<100, 2><<<(2 * rows + 3) / 4, 256, 0, stream>>>(hbB, post_b, 2 * rows);
        k_mgemm<7, true, false><<<gb, 256, 0, stream>>>(post_b, Wm_o1, bo1, hbB, rows, 224);
        merge_comb<<<ga, 256, 0, stream>>>(hbA, hbB, Wl1, bl1, h1 + (size_t)n0 * 200,
                                           h1_bf + (size_t)n0 * 224, rows);
    }

    // ---- relation layer ----
    k_gedges_b<<<M, 384, 0, stream>>>(rsT, csT, offsT, x, invn, g, gcomb, M);
    k_mgemm<14, true, false><<<gM64, 256, 0, stream>>>(gcomb, Wrf_b, brf, gp, M, 448);

    // ---- hop 2 setup ----
    k_watt<<<(600 + 255) / 256, 256, 0, stream>>>(att_in2, W_in2, wa_in, 1, 200, 600);
    k_watt<<<(600 + 255) / 256, 256, 0, stream>>>(att_out2, W_out2, wa_out, 1, 200, 600);
    k_dots<true><<<gN4, 256, 0, stream>>>(h1, nullptr, wa_in, rdot_in, cdot_in, N);
    k_dots<true><<<gN4, 256, 0, stream>>>(h1, nullptr, wa_out, rdot_out, cdot_out, N);
    k_gdot<<<(M + 255) / 256, 256, 0, stream>>>(gp, wa_in, gdot_in, M, 1, 200, 600);
    k_gdot<<<(M + 255) / 256, 256, 0, stream>>>(gp, wa_out, gdot_out, M, 1, 200, 600);
    // gp bf16 [M][224] reusing gcomb
    k_h1b<<<((int)(((size_t)M * 224 + 255) / 256)), 256, 0, stream>>>(gp, gcomb, M);
    k_ew_s<<<(E + 255) / 256, 256, 0, stream>>>(nbrS_in, keyS_in, etS_in, rdot_in, cdot_in, gdot_in, ewS_in, E, 1);
    k_ew_s<<<(E + 255) / 256, 256, 0, stream>>>(nbrS_out, keyS_out, etS_out, cdot_out, rdot_out, gdot_out, ewS_out, E, 1);

    for (int n0 = 0; n0 < N; n0 += C) {
        int rows = (N - n0 < C) ? (N - n0) : C;
        int n1 = n0 + rows;
        int ga = (rows + 3) / 4;
        int gb = (rows + 63) / 64;
        k_agg<true><<<ga, 256, 0, stream>>>(offs_in, nbrS_in, etS_in, ewS_in, h1_bf, gcomb, Ac, n0, n1);
        k_mgemm<21, false, false><<<gb, 256, 0, stream>>>(Ac, Wc_in2, nullptr, hbA, rows, 672);
        gat_post2<200, 1><<<ga, 256, 0, stream>>>(hbA, post_b, rows);
        k_mgemm<7, true, false><<<gb, 256, 0, stream>>>(post_b, Wm_i2, bi2, hbA, rows, 224);
        k_agg<true><<<ga, 256, 0, stream>>>(offs_out, nbrS_out, etS_out, ewS_out, h1_bf, gcomb, Ac, n0, n1);
        k_mgemm<21, false, false><<<gb, 256, 0, stream>>>(Ac, Wc_out2, nullptr, hbB, rows, 672);
        gat_post2<200, 1><<<ga, 256, 0, stream>>>(hbB, post_b, rows);
        k_mgemm<7, true, false><<<gb, 256, 0, stream>>>(post_b, Wm_o2, bo2, hbB, rows, 224);
        merge_comb<<<ga, 256, 0, stream>>>(hbA, hbB, Wl2, bl2, out + (size_t)n0 * 200, nullptr, rows);
        // entity residual: out += l2norm(x) @ W_ent^T  (A = xn_bf, lda=112; W cols >=100 are zero)
        k_mgemm<4, false, true><<<gb, 256, 0, stream>>>(xn_bf + (size_t)n0 * 112, Wb_ent, nullptr,
                                                        out + (size_t)n0 * 200, rows, 112);
    }
}

// Round 4
// 2859.406 us; speedup vs baseline: 1.2632x; 1.0097x over previous
//
#include <hip/hip_runtime.h>
#include <cstddef>
#include <cstdint>

#define WSLOPE 0.2f
#define WEPS 1e-12f

typedef __attribute__((ext_vector_type(8))) short bf16x8;
typedef __attribute__((ext_vector_type(4))) float f32x4;

__device__ __forceinline__ float waveSum(float v) {
#pragma unroll
    for (int off = 32; off > 0; off >>= 1) v += __shfl_xor(v, off, 64);
    return v;
}
// reduce across the 16 llo lanes (same lhi group)
__device__ __forceinline__ float rowSum16(float v) {
#pragma unroll
    for (int off = 8; off > 0; off >>= 1) v += __shfl_xor(v, off, 64);
    return v;
}
__device__ __forceinline__ float eluf(float v) { return v > 0.f ? v : expm1f(v); }
__device__ __forceinline__ short f2bf(float f) {
    union { float f; uint32_t u; } v; v.f = f;
    uint32_t r = v.u + 0x7FFF + ((v.u >> 16) & 1);
    return (short)(r >> 16);
}
__device__ __forceinline__ float bf2f(short s) {
    union { uint32_t u; float f; } v; v.u = ((uint32_t)(uint16_t)s) << 16;
    return v.f;
}

// ---------------- per-node inverse L2 norm of x ----------------
__global__ void k_invnorm(const float* __restrict__ x, float* __restrict__ invn, int N) {
    int wid = blockIdx.x * 4 + (threadIdx.x >> 6);
    int lane = threadIdx.x & 63;
    if (wid >= N) return;
    const float* p = x + (size_t)wid * 100;
    float a = p[lane];
    float ss = a * a;
    if (lane < 36) { float b = p[lane + 64]; ss += b * b; }
    ss = waveSum(ss);
    if (lane == 0) invn[wid] = 1.f / fmaxf(sqrtf(ss), WEPS);
}

// ---------------- generic CSR build (counting sort) ----------------
__global__ void k_count(const int* __restrict__ keys, int* __restrict__ cnt, int n) {
    int i = blockIdx.x * 256 + threadIdx.x;
    if (i < n) atomicAdd(&cnt[keys[i]], 1);
}

#define SCAN_CHUNK 2048
__global__ void k_blocksum(const int* __restrict__ cnt, int* __restrict__ bsum, int n) {
    __shared__ int sh[256];
    int b = blockIdx.x, t = threadIdx.x;
    int base = b * SCAN_CHUNK;
    int s = 0;
    for (int i = t; i < SCAN_CHUNK; i += 256) { int idx = base + i; if (idx < n) s += cnt[idx]; }
    sh[t] = s; __syncthreads();
    for (int off = 128; off > 0; off >>= 1) { if (t < off) sh[t] += sh[t + off]; __syncthreads(); }
    if (t == 0) bsum[b] = sh[0];
}

__global__ void k_scanwrite(const int* __restrict__ cnt, const int* __restrict__ bsum,
                            int* __restrict__ offs, int* __restrict__ cur, int n, int nb) {
    __shared__ int sh[256];
    __shared__ int sbase;
    int b = blockIdx.x, t = threadIdx.x;
    if (t == 0) { int s = 0; for (int i = 0; i < b; ++i) s += bsum[i]; sbase = s; }
    __syncthreads();
    int base = b * SCAN_CHUNK;
    int loc[8]; int ts = 0;
#pragma unroll
    for (int i = 0; i < 8; ++i) { int idx = base + t * 8 + i; int v = (idx < n) ? cnt[idx] : 0; loc[i] = ts; ts += v; }
    sh[t] = ts; __syncthreads();
    for (int off = 1; off < 256; off <<= 1) {
        int v = (t >= off) ? sh[t - off] : 0;
        __syncthreads();
        sh[t] += v;
        __syncthreads();
    }
    int excl = (t == 0) ? 0 : sh[t - 1];
    int gbase = sbase + excl;
#pragma unroll
    for (int i = 0; i < 8; ++i) {
        int idx = base + t * 8 + i;
        if (idx < n) { offs[idx] = gbase + loc[i]; cur[idx] = gbase + loc[i]; }
    }
    if (b == nb - 1 && t == 255) offs[n] = sbase + sh[255];
}

__global__ void k_scatter3(const int* __restrict__ keys, const int* __restrict__ other,
                           const int* __restrict__ et, int* __restrict__ cur,
                           int* __restrict__ nbrS, int* __restrict__ etS,
                           int* __restrict__ keyS, int n) {
    int i = blockIdx.x * 256 + threadIdx.x;
    if (i < n) {
        int p = atomicAdd(&cur[keys[i]], 1);
        nbrS[p] = other[i];
        etS[p] = et[i];
        keyS[p] = keys[i];
    }
}

__global__ void k_scatter2(const int* __restrict__ keys, int* __restrict__ cur,
                           int* __restrict__ rs, int* __restrict__ cs,
                           const int* __restrict__ row, const int* __restrict__ col, int n) {
    int i = blockIdx.x * 256 + threadIdx.x;
    if (i < n) {
        int p = atomicAdd(&cur[keys[i]], 1);
        rs[p] = row[i];
        cs[p] = col[i];
    }
}

// ---------------- attention vector ----------------
__global__ void k_watt(const float* __restrict__ att, const float* __restrict__ W,
                       float* __restrict__ wa, int H, int DH, int K) {
    int id = blockIdx.x * 256 + threadIdx.x;
    if (id >= H * K) return;
    int h = id / K, k = id % K;
    float s = 0.f;
    for (int j = 0; j < DH; ++j) s += att[h * DH + j] * W[(size_t)(h * DH + j) * K + k];
    wa[id] = s;
}

// ---------------- hop1 per-node dots: both directions in one pass over x ----------------
__global__ void k_dots2(const float* __restrict__ x, const float* __restrict__ invn,
                        const float* __restrict__ wai, const float* __restrict__ wao,
                        float* __restrict__ rdi, float* __restrict__ cdi,
                        float* __restrict__ rdo, float* __restrict__ cdo, int N) {
    int wid = blockIdx.x * 4 + (threadIdx.x >> 6);
    int lane = threadIdx.x & 63;
    if (wid >= N) return;
    float inv = invn[wid];
    const float* p = x + (size_t)wid * 100;
    float f0 = p[lane] * inv;
    float f1 = (lane < 36) ? p[lane + 64] * inv : 0.f;
#pragma unroll
    for (int h = 0; h < 2; ++h) {
        const float* wi = wai + h * 300;
        const float* wo = wao + h * 300;
        float ri = f0 * wi[lane] + ((lane < 36) ? f1 * wi[lane + 64] : 0.f);
        float ci = f0 * wi[100 + lane] + ((lane < 36) ? f1 * wi[100 + lane + 64] : 0.f);
        float ro = f0 * wo[lane] + ((lane < 36) ? f1 * wo[lane + 64] : 0.f);
        float co = f0 * wo[100 + lane] + ((lane < 36) ? f1 * wo[100 + lane + 64] : 0.f);
        ri = waveSum(ri); ci = waveSum(ci); ro = waveSum(ro); co = waveSum(co);
        if (lane == 0) { rdi[wid * 2 + h] = ri; cdi[wid * 2 + h] = ci; rdo[wid * 2 + h] = ro; cdo[wid * 2 + h] = co; }
    }
}

// ---------------- hop1 per-type g dots: 4 dots in one pass over g ----------------
__global__ void k_gdot4(const float* __restrict__ g, const float* __restrict__ wai,
                        const float* __restrict__ wao, float* __restrict__ gdi,
                        float* __restrict__ gdo, int M) {
    int m = blockIdx.x * 256 + threadIdx.x;
    if (m >= M) return;
    const float* gm = g + (size_t)m * 100;
    float s0 = 0.f, s1 = 0.f, s2 = 0.f, s3 = 0.f;
    for (int k = 0; k < 100; ++k) {
        float v = gm[k];
        s0 += v * wai[200 + k]; s1 += v * wai[500 + k];
        s2 += v * wao[200 + k]; s3 += v * wao[500 + k];
    }
    gdi[m * 2] = s0; gdi[m * 2 + 1] = s1;
    gdo[m * 2] = s2; gdo[m * 2 + 1] = s3;
}

// ---------------- per-edge weight, written in CSR-sorted order ----------------
__global__ void k_ew_s(const int* __restrict__ nbrS, const int* __restrict__ keyS,
                       const int* __restrict__ etS,
                       const float* __restrict__ ndot, const float* __restrict__ kdot,
                       const float* __restrict__ gdot, float* __restrict__ ewS, int E, int H) {
    int id = blockIdx.x * 256 + threadIdx.x;
    if (id >= E * H) return;
    int p = id / H, h = id - p * H;
    float a = ndot[nbrS[p] * H + h] + kdot[keyS[p] * H + h] + gdot[etS[p] * H + h];
    float lr = a > 0.f ? a : WSLOPE * a;
    ewS[id] = expf(-lr);
}

// ---------------- CSR aggregation: wave per node, bf16 gathers, combined A-row ----------------
// HOP1: A row [576] = [agg 224 blockdiag | z0 112 | z1 112 | self 128]
// HOP2: A row [672] = [agg 224           | z 224            | self 224]
template<bool HOP2>
__global__ void k_agg(const int* __restrict__ offs, const int* __restrict__ nbrS,
                      const int* __restrict__ etS, const float* __restrict__ ewS,
                      const short* __restrict__ featB, const short* __restrict__ gB,
                      short* __restrict__ A, int n0, int n1) {
    constexpr int H = HOP2 ? 1 : 2;
    constexpr int LDA = HOP2 ? 672 : 576;
    constexpr int FW = HOP2 ? 224 : 112;
    constexpr int GW = HOP2 ? 224 : 112;
    int node = n0 + blockIdx.x * 4 + (threadIdx.x >> 6);
    int lane = threadIdx.x & 63;
    if (node >= n1) return;
    int o = offs[node];
    int deg = offs[node + 1] - o;
    float va[7];
#pragma unroll
    for (int m = 0; m < 7; ++m) va[m] = 0.f;
    if (deg > 0) {
        float s0 = 0.f, s1 = 0.f;
        for (int i = lane; i < deg; i += 64) {
            s0 += ewS[(size_t)(o + i) * H];
            if (H == 2) s1 += ewS[(size_t)(o + i) * H + 1];
        }
        s0 = waveSum(s0);
        float rd0 = 1.f / s0, rd1 = rd0;
        if (H == 2) { s1 = waveSum(s1); rd1 = 1.f / s1; }
        for (int j = 0; j < deg; ++j) {
            float a0 = ewS[(size_t)(o + j) * H] * rd0;
            float a1 = (H == 2) ? ewS[(size_t)(o + j) * H + 1] * rd1 : a0;
            int nbr = nbrS[o + j];
            int et = etS[o + j];
            const short* fr = featB + (size_t)nbr * FW;
            const short* gr = gB + (size_t)et * GW;
            if (!HOP2) {
#pragma unroll
                for (int m = 0; m < 7; ++m) {
                    int d = lane + m * 64;
                    if (d < 100) va[m] += a0 * bf2f(fr[d]);
                    else if (d < 200) va[m] += a1 * bf2f(fr[d - 100]);
                    else if (d < 300) va[m] += a0 * bf2f(gr[d - 200]);
                    else if (d < 400) va[m] += a1 * bf2f(gr[d - 300]);
                }
            } else {
#pragma unroll
                for (int m = 0; m < 7; ++m) {
                    int d = lane + m * 64;
                    if (d < 200) va[m] += a0 * bf2f(fr[d]);
                    else if (d < 424) va[m] += a0 * bf2f(gr[d - 200]);
                }
            }
        }
    }
    size_t rb = (size_t)(node - n0);
    short* Ar = A + rb * LDA;
    if (!HOP2) {
#pragma unroll
        for (int m = 0; m < 7; ++m) {
            int d = lane + m * 64;
            if (d < 400) {
                int col = d < 100 ? d : (d < 200 ? d + 12 : (d < 300 ? d + 24 : d + 36));
                Ar[col] = f2bf(va[m]);
            }
        }
        if (lane < 48) { int q = lane / 12; int rm = lane - q * 12; Ar[q * 112 + 100 + rm] = 0; }
        const short* sf = featB + (size_t)node * 112;
#pragma unroll
        for (int mm = 0; mm < 2; ++mm) {
            int k = lane + mm * 64;
            if (k < 128) Ar[448 + k] = (deg > 0 && k < 112) ? sf[k] : (short)0;
        }
    } else {
#pragma unroll
        for (int m = 0; m < 7; ++m) {
            int d = lane + m * 64;
            if (d < 424) Ar[d < 200 ? d : d + 24] = f2bf(va[m]);
        }
        if (lane < 24) Ar[200 + lane] = 0;
        const short* sf = featB + (size_t)node * 224;
#pragma unroll
        for (int mm = 0; mm < 4; ++mm) {
            int k = lane + mm * 64;
            if (k < 224) Ar[448 + k] = deg > 0 ? sf[k] : (short)0;
        }
    }
}

// ---------------- plain bf16 MFMA GEMM (used for entity residual) ----------------
template<int KSTEPS, bool BIAS, bool ACC>
__launch_bounds__(256)
__global__ void k_mgemm(const short* __restrict__ A, const short* __restrict__ Wb,
                        const float* __restrict__ bias,
                        float* __restrict__ out, int rows, int lda) {
    constexpr int LDW = KSTEPS * 32;
    const int t = threadIdx.x;
    const int wv = t >> 6, l = t & 63;
    const int lhi = l >> 4, llo = l & 15;
    const int rbase = blockIdx.x * 64 + wv * 16;
    f32x4 acc[13];
#pragma unroll
    for (int j = 0; j < 13; ++j) acc[j] = f32x4{0.f, 0.f, 0.f, 0.f};
    const short* arow = A + (size_t)(rbase + llo) * lda + lhi * 8;
#pragma unroll
    for (int kt = 0; kt < KSTEPS; ++kt) {
        bf16x8 a = *(const bf16x8*)(arow + kt * 32);
#pragma unroll
        for (int j = 0; j < 13; ++j) {
            bf16x8 b = *(const bf16x8*)(Wb + (size_t)(j * 16 + llo) * LDW + kt * 32 + lhi * 8);
            acc[j] = __builtin_amdgcn_mfma_f32_16x16x32_bf16(a, b, acc[j], 0, 0, 0);
        }
    }
    const int r0 = rbase + lhi * 4;
#pragma unroll
    for (int e = 0; e < 4; ++e) {
        int r = r0 + e;
        if (r >= rows) continue;
        float* orow = out + (size_t)r * 200;
#pragma unroll
        for (int j = 0; j < 13; ++j) {
            int d = j * 16 + llo;
            if (d < 200) {
                float v = acc[j][e];
                if (BIAS) v += bias[d];
                if (ACC) v += orow[d];
                orow[d] = v;
            }
        }
    }
}

// ---------------- agg GEMM with fused elu + per-head l2norm -> bf16 post ----------------
template<int KSTEPS, int H>
__launch_bounds__(256)
__global__ void k_mgemm_post(const short* __restrict__ A, const short* __restrict__ Wb,
                             short* __restrict__ post, int rows, int lda) {
    constexpr int LDW = KSTEPS * 32;
    const int t = threadIdx.x;
    const int wv = t >> 6, l = t & 63;
    const int lhi = l >> 4, llo = l & 15;
    const int rbase = blockIdx.x * 64 + wv * 16;
    f32x4 acc[13];
#pragma unroll
    for (int j = 0; j < 13; ++j) acc[j] = f32x4{0.f, 0.f, 0.f, 0.f};
    const short* arow = A + (size_t)(rbase + llo) * lda + lhi * 8;
#pragma unroll
    for (int kt = 0; kt < KSTEPS; ++kt) {
        bf16x8 a = *(const bf16x8*)(arow + kt * 32);
#pragma unroll
        for (int j = 0; j < 13; ++j) {
            bf16x8 b = *(const bf16x8*)(Wb + (size_t)(j * 16 + llo) * LDW + kt * 32 + lhi * 8);
            acc[j] = __builtin_amdgcn_mfma_f32_16x16x32_bf16(a, b, acc[j], 0, 0, 0);
        }
    }
    const int r0 = rbase + lhi * 4;
#pragma unroll
    for (int e = 0; e < 4; ++e) {
        int r = r0 + e;
        if (r >= rows) continue;
        float v[13];
        float s0 = 0.f, s1 = 0.f;
#pragma unroll
        for (int j = 0; j < 13; ++j) {
            int d = j * 16 + llo;
            if (d < 200) {
                float xv = eluf(acc[j][e]);
                v[j] = xv;
                if (H == 1 || d < 100) s0 += xv * xv; else s1 += xv * xv;
            }
        }
        s0 = rowSum16(s0);
        float inv0 = 1.f / fmaxf(sqrtf(s0), WEPS);
        float inv1 = inv0;
        if (H == 2) { s1 = rowSum16(s1); inv1 = 1.f / fmaxf(sqrtf(s1), WEPS); }
        short* pr = post + (size_t)r * 224;
#pragma unroll
        for (int j = 0; j < 13; ++j) {
            int d = j * 16 + llo;
            if (d < 200) pr[d] = f2bf(v[j] * ((H == 2 && d >= 100) ? inv1 : inv0));
        }
    }
}

// ---------------- fused merge: both GEMMs + lambda + elu + l2norm (+hop2 dots) ----------------
template<bool HOP1>
__launch_bounds__(256)
__global__ void k_mergemm(const short* __restrict__ pA, const short* __restrict__ pB,
                          const short* __restrict__ Wi, const short* __restrict__ Wo,
                          const float* __restrict__ bi, const float* __restrict__ bo,
                          const float* __restrict__ Wl, const float* __restrict__ bl,
                          float* __restrict__ outf, short* __restrict__ h1b,
                          const float* __restrict__ wa2i, const float* __restrict__ wa2o,
                          float* __restrict__ rdi, float* __restrict__ cdi,
                          float* __restrict__ rdo, float* __restrict__ cdo,
                          int rows) {
    const int t = threadIdx.x;
    const int wv = t >> 6, l = t & 63;
    const int lhi = l >> 4, llo = l & 15;
    const int rbase = blockIdx.x * 64 + wv * 16;
    f32x4 accA[13], accB[13];
#pragma unroll
    for (int j = 0; j < 13; ++j) { accA[j] = f32x4{0.f, 0.f, 0.f, 0.f}; accB[j] = f32x4{0.f, 0.f, 0.f, 0.f}; }
    const short* aA = pA + (size_t)(rbase + llo) * 224 + lhi * 8;
    const short* aB = pB + (size_t)(rbase + llo) * 224 + lhi * 8;
#pragma unroll
    for (int kt = 0; kt < 7; ++kt) {
        bf16x8 a1 = *(const bf16x8*)(aA + kt * 32);
        bf16x8 a2 = *(const bf16x8*)(aB + kt * 32);
#pragma unroll
        for (int j = 0; j < 13; ++j) {
            bf16x8 b1 = *(const bf16x8*)(Wi + (size_t)(j * 16 + llo) * 224 + kt * 32 + lhi * 8);
            accA[j] = __builtin_amdgcn_mfma_f32_16x16x32_bf16(a1, b1, accA[j], 0, 0, 0);
            bf16x8 b2 = *(const bf16x8*)(Wo + (size_t)(j * 16 + llo) * 224 + kt * 32 + lhi * 8);
            accB[j] = __builtin_amdgcn_mfma_f32_16x16x32_bf16(a2, b2, accB[j], 0, 0, 0);
        }
    }
    const int r0 = rbase + lhi * 4;
    float blv = bl[0];
#pragma unroll
    for (int e = 0; e < 4; ++e) {
        int r = r0 + e;
        if (r >= rows) continue;
        float vi[13], vo[13];
        float lp = 0.f;
#pragma unroll
        for (int j = 0; j < 13; ++j) {
            int d = j * 16 + llo;
            if (d < 200) {
                vi[j] = accA[j][e] + bi[d];
                vo[j] = accB[j][e] + bo[d];
                lp += Wl[d] * vi[j] + Wl[200 + d] * vo[j];
            }
        }
        lp = rowSum16(lp);
        float lam = 1.f / (1.f + expf(-(lp + blv)));
        float hv[13];
        float ss = 0.f;
#pragma unroll
        for (int j = 0; j < 13; ++j) {
            int d = j * 16 + llo;
            if (d < 200) { hv[j] = eluf(lam * vi[j] + (1.f - lam) * vo[j]); ss += hv[j] * hv[j]; }
        }
        ss = rowSum16(ss);
        float inv = 1.f / fmaxf(sqrtf(ss), WEPS);
        float ri = 0.f, ci = 0.f, ro = 0.f, co = 0.f;
#pragma unroll
        for (int j = 0; j < 13; ++j) {
            int d = j * 16 + llo;
            if (d < 200) {
                float val = hv[j] * inv;
                if (HOP1) {
                    h1b[(size_t)r * 224 + d] = f2bf(val);
                    ri += val * wa2i[d]; ci += val * wa2i[200 + d];
                    ro += val * wa2o[d]; co += val * wa2o[200 + d];
                } else {
                    outf[(size_t)r * 200 + d] = val;
                }
            } else if (HOP1) {
                h1b[(size_t)r * 224 + d] = 0;   // d in [200,208)
            }
        }
        if (HOP1) {
            h1b[(size_t)r * 224 + 208 + llo] = 0;
            ri = rowSum16(ri); ci = rowSum16(ci); ro = rowSum16(ro); co = rowSum16(co);
            if (llo == 0) { rdi[r] = ri; cdi[r] = ci; rdo[r] = ro; cdo[r] = co; }
        }
    }
}

// ---------------- relation GEMM: fused bias + bf16 gp write + hop2 gdots ----------------
__launch_bounds__(256)
__global__ void k_mgemm_rel(const short* __restrict__ A, const short* __restrict__ Wb,
                            const float* __restrict__ brf,
                            short* __restrict__ gout, const float* __restrict__ wai,
                            const float* __restrict__ wao,
                            float* __restrict__ gdi, float* __restrict__ gdo, int rows) {
    constexpr int KSTEPS = 14, LDW = KSTEPS * 32;
    const int t = threadIdx.x;
    const int wv = t >> 6, l = t & 63;
    const int lhi = l >> 4, llo = l & 15;
    const int rbase = blockIdx.x * 64 + wv * 16;
    f32x4 acc[13];
#pragma unroll
    for (int j = 0; j < 13; ++j) acc[j] = f32x4{0.f, 0.f, 0.f, 0.f};
    const short* arow = A + (size_t)(rbase + llo) * 448 + lhi * 8;
#pragma unroll
    for (int kt = 0; kt < KSTEPS; ++kt) {
        bf16x8 a = *(const bf16x8*)(arow + kt * 32);
#pragma unroll
        for (int j = 0; j < 13; ++j) {
            bf16x8 b = *(const bf16x8*)(Wb + (size_t)(j * 16 + llo) * LDW + kt * 32 + lhi * 8);
            acc[j] = __builtin_amdgcn_mfma_f32_16x16x32_bf16(a, b, acc[j], 0, 0, 0);
        }
    }
    const int r0 = rbase + lhi * 4;
#pragma unroll
    for (int e = 0; e < 4; ++e) {
        int r = r0 + e;
        if (r >= rows) continue;
        short* pr = gout + (size_t)r * 224;
        float gi = 0.f, go = 0.f;
#pragma unroll
        for (int j = 0; j < 13; ++j) {
            int d = j * 16 + llo;
            if (d < 200) {
                float val = acc[j][e] + brf[d];
                pr[d] = f2bf(val);
                gi += val * wai[400 + d];
                go += val * wao[400 + d];
            } else {
                pr[d] = 0;   // d in [200,208)
            }
        }
        pr[208 + llo] = 0;
        gi = rowSum16(gi); go = rowSum16(go);
        if (llo == 0) { gdi[r] = gi; gdo[r] = go; }
    }
}

// ---------------- weight prep ----------------
__global__ void k_prepw(const float* __restrict__ W, int ldW, int koff, int Klen, int span,
                        int mode, short* __restrict__ Wb, int ldWb, int dst) {
    int id = blockIdx.x * 256 + threadIdx.x;
    int tot = 208 * span;
    if (id >= tot) return;
    int d = id / span, k = id - d * span;
    float v = 0.f;
    if (d < 200) {
        if (mode == 0) { if (k < Klen) v = W[(size_t)d * ldW + koff + k]; }
        else { int h = d / 100; int kk = k - h * 112; if (kk >= 0 && kk < Klen) v = W[(size_t)d * ldW + koff + kk]; }
    }
    Wb[(size_t)d * ldWb + dst + k] = f2bf(v);
}

__global__ void k_prepwrf(const float* __restrict__ Wr, const float* __restrict__ Wf,
                          short* __restrict__ Wb) {
    int id = blockIdx.x * 256 + threadIdx.x;
    if (id >= 208 * 448) return;
    int d = id / 448, k = id - d * 448;
    float v = 0.f;
    if (d < 200) {
        if (k < 100) v = Wr[(size_t)d * 100 + k];
        else if (k >= 128 && k < 428) v = Wf[(size_t)d * 300 + (k - 128)];
    }
    Wb[id] = f2bf(v);
}

__global__ void k_brf(const float* __restrict__ br, const float* __restrict__ bf,
                      float* __restrict__ brf) {
    int d = threadIdx.x;
    if (d < 200) brf[d] = br[d] + bf[d];
}

// ---------------- converts ----------------
__global__ void k_cvt112(const float* __restrict__ src, const float* __restrict__ invn,
                         short* __restrict__ dst, int rows) {
    int id = blockIdx.x * 256 + threadIdx.x;
    if (id >= rows * 112) return;
    int r = id / 112, k = id - r * 112;
    float v = 0.f;
    if (k < 100) { v = src[(size_t)r * 100 + k]; if (invn) v *= invn[r]; }
    dst[id] = f2bf(v);
}

__global__ void k_gcb(const float* __restrict__ g, short* __restrict__ gb, int rows) {
    int id = blockIdx.x * 256 + threadIdx.x;
    if (id >= rows * 128) return;
    int r = id >> 7, k = id & 127;
    gb[(size_t)r * 448 + k] = f2bf(k < 100 ? g[(size_t)r * 100 + k] : 0.f);
}

// ---------------- relation layer: block per type, 384 threads ----------------
__global__ void k_gedges_b(const int* __restrict__ rsT, const int* __restrict__ csT,
                           const int* __restrict__ offsT,
                           const float* __restrict__ x, const float* __restrict__ invn,
                           const float* __restrict__ g, short* __restrict__ gcomb, int M) {
    __shared__ float red[6];
    int m = blockIdx.x, t = threadIdx.x;
    int o = offsT[m];
    int deg = offsT[m + 1] - o;
    float acc = 0.f;
    if (t < 128) {
        int d = t; bool ok = d < 100;
        for (int i = 0; i < deg; ++i) {
            int r = rsT[o + i];
            if (ok) acc += x[(size_t)r * 100 + d] * invn[r];
        }
    } else if (t < 256) {
        int d = t - 128; bool ok = d < 100;
        for (int i = 0; i < deg; ++i) {
            int c = csT[o + i];
            if (ok) acc += x[(size_t)c * 100 + d] * invn[c];
        }
    } else {
        int d = t - 256;
        if (d < 100) acc = (float)deg * g[(size_t)m * 100 + d];
    }
    float sq = waveSum(acc * acc);
    if ((t & 63) == 0) red[t >> 6] = sq;
    __syncthreads();
    float s2 = red[0] + red[1] + red[2] + red[3] + red[4] + red[5];
    float inv = 1.f / fmaxf(sqrtf(s2), WEPS);
    short* orow = gcomb + (size_t)m * 448 + 128;
    if (t < 128) {
        if (t < 100) orow[t] = f2bf(eluf(acc * inv));
    } else if (t < 256) {
        int d = t - 128;
        if (d < 100) orow[100 + d] = f2bf(eluf(acc * inv));
    } else {
        int d = t - 256;
        if (d < 100) orow[200 + d] = f2bf(eluf(acc * inv));
        else if (d < 120) orow[200 + d] = 0;
    }
}

// ---------------- host launch ----------------
extern "C" void kernel_launch(void* const* d_in, const int* in_sizes, int n_in,
                              void* d_out, int out_size, void* d_ws, size_t ws_size,
                              hipStream_t stream) {
    const int* eidx   = (const int*)d_in[0];
    const int* etype  = (const int*)d_in[1];
    const float* x    = (const float*)d_in[5];
    const float* g    = (const float*)d_in[6];
    const float* W_in1  = (const float*)d_in[7];
    const float* att_in1 = (const float*)d_in[8];
    const float* W_out1 = (const float*)d_in[9];
    const float* att_out1 = (const float*)d_in[10];
    const float* Wi1 = (const float*)d_in[11]; const float* bi1 = (const float*)d_in[12];
    const float* Wo1 = (const float*)d_in[13]; const float* bo1 = (const float*)d_in[14];
    const float* Wl1 = (const float*)d_in[15]; const float* bl1 = (const float*)d_in[16];
    const float* Wr  = (const float*)d_in[17]; const float* br  = (const float*)d_in[18];
    const float* Wf  = (const float*)d_in[19]; const float* bf  = (const float*)d_in[20];
    const float* W_in2  = (const float*)d_in[21]; const float* att_in2 = (const float*)d_in[22];
    const float* W_out2 = (const float*)d_in[23]; const float* att_out2 = (const float*)d_in[24];
    const float* Wi2 = (const float*)d_in[25]; const float* bi2 = (const float*)d_in[26];
    const float* Wo2 = (const float*)d_in[27]; const float* bo2 = (const float*)d_in[28];
    const float* Wl2 = (const float*)d_in[29]; const float* bl2 = (const float*)d_in[30];
    const float* W_ent = (const float*)d_in[31];

    const int E = in_sizes[1];
    const int N = in_sizes[5] / 100;
    const int M = in_sizes[6] / 100;
    const int Mr = (M + 63) & ~63;
    float* out = (float*)d_out;
    const int* row = eidx;
    const int* col = eidx + E;

    char* w = (char*)d_ws;
    size_t off_b = 0;
    auto alloc = [&](size_t bytes) -> void* {
        void* p = w + off_b;
        off_b += (bytes + 255) & ~(size_t)255;
        return p;
    };
    float* invn  = (float*)alloc((size_t)N * 4);
    short* h1_bf = (short*)alloc((size_t)(N + 64) * 224 * 2);
    short* xn_bf = (short*)alloc((size_t)(N + 64) * 112 * 2);
    short* g_bf  = (short*)alloc((size_t)M * 112 * 2);
    short* gp_bf = (short*)alloc((size_t)Mr * 224 * 2);
    int* offs_in = (int*)alloc((size_t)(N + 1) * 4);
    int* offs_out= (int*)alloc((size_t)(N + 1) * 4);
    int* offsT   = (int*)alloc((size_t)(M + 1) * 4);
    int* nbrS_in = (int*)alloc((size_t)E * 4);
    int* etS_in  = (int*)alloc((size_t)E * 4);
    int* keyS_in = (int*)alloc((size_t)E * 4);
    int* nbrS_out= (int*)alloc((size_t)E * 4);
    int* etS_out = (int*)alloc((size_t)E * 4);
    int* keyS_out= (int*)alloc((size_t)E * 4);
    int* rsT     = (int*)alloc((size_t)E * 4);
    int* csT     = (int*)alloc((size_t)E * 4);
    int* cnt     = (int*)alloc((size_t)N * 4);
    int* cur     = (int*)alloc((size_t)N * 4);
    int* bsum    = (int*)alloc((size_t)64 * 4);
    float* wa1_in = (float*)alloc((size_t)640 * 4);
    float* wa1_out= (float*)alloc((size_t)640 * 4);
    float* wa2_in = (float*)alloc((size_t)640 * 4);
    float* wa2_out= (float*)alloc((size_t)640 * 4);
    float* rdot_in = (float*)alloc((size_t)N * 2 * 4);
    float* cdot_in = (float*)alloc((size_t)N * 2 * 4);
    float* rdot_out= (float*)alloc((size_t)N * 2 * 4);
    float* cdot_out= (float*)alloc((size_t)N * 2 * 4);
    float* gdot_in = (float*)alloc((size_t)M * 2 * 4);
    float* gdot_out= (float*)alloc((size_t)M * 2 * 4);
    float* ewS_in  = (float*)alloc((size_t)E * 2 * 4);
    float* ewS_out = (float*)alloc((size_t)E * 2 * 4);
    // relation A buffer [Mr][448]: cols 0..127 g bf16, 128..447 ge_n bf16
    short* gcomb   = (short*)alloc((size_t)Mr * 448 * 2);
    // bf16 weight buffers
    short* Wc_in1  = (short*)alloc((size_t)208 * 576 * 2);
    short* Wc_out1 = (short*)alloc((size_t)208 * 576 * 2);
    short* Wc_in2  = (short*)alloc((size_t)208 * 672 * 2);
    short* Wc_out2 = (short*)alloc((size_t)208 * 672 * 2);
    short* Wm_i1   = (short*)alloc((size_t)208 * 224 * 2);
    short* Wm_o1   = (short*)alloc((size_t)208 * 224 * 2);
    short* Wm_i2   = (short*)alloc((size_t)208 * 224 * 2);
    short* Wm_o2   = (short*)alloc((size_t)208 * 224 * 2);
    short* Wb_ent  = (short*)alloc((size_t)208 * 128 * 2);
    short* Wrf_b   = (short*)alloc((size_t)208 * 448 * 2);
    float* brf     = (float*)alloc((size_t)200 * 4);

    // chunk buffers: per-row 1344(Ac) + 448(postA) + 448(postB) = 2240 B
    if (off_b >= ws_size) return;
    size_t rem = ws_size - off_b;
    long long Cll = (long long)(rem / 2368);
    long long Nr64 = ((long long)N + 63) & ~63LL;
    int C = (int)(Cll > Nr64 ? Nr64 : Cll);
    C &= ~63;
    if (C < 64) return;
    short* Ac    = (short*)alloc((size_t)C * 672 * 2);
    short* postA = (short*)alloc((size_t)C * 224 * 2);
    short* postB = (short*)alloc((size_t)C * 224 * 2);
    if (off_b > ws_size) return;

    const int gE = (E + 255) / 256;
    const int gN4 = (N + 3) / 4;
    const int gM64 = (M + 63) / 64;

    k_invnorm<<<gN4, 256, 0, stream>>>(x, invn, N);

    // zero pad cols of post buffers once (epilogues never write k>=200... pads stay 0)
    hipMemsetAsync(postA, 0, (size_t)C * 224 * 2, stream);
    hipMemsetAsync(postB, 0, (size_t)C * 224 * 2, stream);

    // ---- bf16 feature tables ----
    k_cvt112<<<((int)(((size_t)N * 112 + 255) / 256)), 256, 0, stream>>>(x, invn, xn_bf, N);
    k_cvt112<<<((int)(((size_t)M * 112 + 255) / 256)), 256, 0, stream>>>(g, nullptr, g_bf, M);

    // ---- weight prep ----
    auto gsp = [](int span) { return (208 * span + 255) / 256; };
    k_prepw<<<gsp(224), 256, 0, stream>>>(W_in1, 300, 0, 100, 224, 1, Wc_in1, 576, 0);
    k_prepw<<<gsp(224), 256, 0, stream>>>(W_in1, 300, 200, 100, 224, 1, Wc_in1, 576, 224);
    k_prepw<<<gsp(128), 256, 0, stream>>>(W_in1, 300, 100, 100, 128, 0, Wc_in1, 576, 448);
    k_prepw<<<gsp(224), 256, 0, stream>>>(W_out1, 300, 100, 100, 224, 1, Wc_out1, 576, 0);
    k_prepw<<<gsp(224), 256, 0, stream>>>(W_out1, 300, 200, 100, 224, 1, Wc_out1, 576, 224);
    k_prepw<<<gsp(128), 256, 0, stream>>>(W_out1, 300, 0, 100, 128, 0, Wc_out1, 576, 448);
    k_prepw<<<gsp(224), 256, 0, stream>>>(W_in2, 600, 0, 200, 224, 0, Wc_in2, 672, 0);
    k_prepw<<<gsp(224), 256, 0, stream>>>(W_in2, 600, 400, 200, 224, 0, Wc_in2, 672, 224);
    k_prepw<<<gsp(224), 256, 0, stream>>>(W_in2, 600, 200, 200, 224, 0, Wc_in2, 672, 448);
    k_prepw<<<gsp(224), 256, 0, stream>>>(W_out2, 600, 200, 200, 224, 0, Wc_out2, 672, 0);
    k_prepw<<<gsp(224), 256, 0, stream>>>(W_out2, 600, 400, 200, 224, 0, Wc_out2, 672, 224);
    k_prepw<<<gsp(224), 256, 0, stream>>>(W_out2, 600, 0, 200, 224, 0, Wc_out2, 672, 448);
    k_prepw<<<gsp(224), 256, 0, stream>>>(Wi1, 200, 0, 200, 224, 0, Wm_i1, 224, 0);
    k_prepw<<<gsp(224), 256, 0, stream>>>(Wo1, 200, 0, 200, 224, 0, Wm_o1, 224, 0);
    k_prepw<<<gsp(224), 256, 0, stream>>>(Wi2, 200, 0, 200, 224, 0, Wm_i2, 224, 0);
    k_prepw<<<gsp(224), 256, 0, stream>>>(Wo2, 200, 0, 200, 224, 0, Wm_o2, 224, 0);
    k_prepw<<<gsp(128), 256, 0, stream>>>(W_ent, 100, 0, 100, 128, 0, Wb_ent, 128, 0);
    k_prepwrf<<<gsp(448), 256, 0, stream>>>(Wr, Wf, Wrf_b);
    k_brf<<<1, 256, 0, stream>>>(br, bf, brf);

    // ---- CSR builds with sorted payloads ----
    int nbN = (N + SCAN_CHUNK - 1) / SCAN_CHUNK;
    int nbM = (M + SCAN_CHUNK - 1) / SCAN_CHUNK;
    hipMemsetAsync(cnt, 0, (size_t)N * 4, stream);
    k_count<<<gE, 256, 0, stream>>>(col, cnt, E);
    k_blocksum<<<nbN, 256, 0, stream>>>(cnt, bsum, N);
    k_scanwrite<<<nbN, 256, 0, stream>>>(cnt, bsum, offs_in, cur, N, nbN);
    k_scatter3<<<gE, 256, 0, stream>>>(col, row, etype, cur, nbrS_in, etS_in, keyS_in, E);

    hipMemsetAsync(cnt, 0, (size_t)N * 4, stream);
    k_count<<<gE, 256, 0, stream>>>(row, cnt, E);
    k_blocksum<<<nbN, 256, 0, stream>>>(cnt, bsum, N);
    k_scanwrite<<<nbN, 256, 0, stream>>>(cnt, bsum, offs_out, cur, N, nbN);
    k_scatter3<<<gE, 256, 0, stream>>>(row, col, etype, cur, nbrS_out, etS_out, keyS_out, E);

    hipMemsetAsync(cnt, 0, (size_t)M * 4, stream);
    k_count<<<gE, 256, 0, stream>>>(etype, cnt, E);
    k_blocksum<<<nbM, 256, 0, stream>>>(cnt, bsum, M);
    k_scanwrite<<<nbM, 256, 0, stream>>>(cnt, bsum, offsT, cur, M, nbM);
    k_scatter2<<<gE, 256, 0, stream>>>(etype, cur, rsT, csT, row, col, E);

    // ---- attention vectors (all four up front; hop2 ones needed by hop1 merge) ----
    k_watt<<<(600 + 255) / 256, 256, 0, stream>>>(att_in1, W_in1, wa1_in, 2, 100, 300);
    k_watt<<<(600 + 255) / 256, 256, 0, stream>>>(att_out1, W_out1, wa1_out, 2, 100, 300);
    k_watt<<<(600 + 255) / 256, 256, 0, stream>>>(att_in2, W_in2, wa2_in, 1, 200, 600);
    k_watt<<<(600 + 255) / 256, 256, 0, stream>>>(att_out2, W_out2, wa2_out, 1, 200, 600);

    // ---- hop 1 setup ----
    k_dots2<<<gN4, 256, 0, stream>>>(x, invn, wa1_in, wa1_out, rdot_in, cdot_in, rdot_out, cdot_out, N);
    k_gdot4<<<(M + 255) / 256, 256, 0, stream>>>(g, wa1_in, wa1_out, gdot_in, gdot_out, M);
    k_ew_s<<<(E * 2 + 255) / 256, 256, 0, stream>>>(nbrS_in, keyS_in, etS_in, rdot_in, cdot_in, gdot_in, ewS_in, E, 2);
    k_ew_s<<<(E * 2 + 255) / 256, 256, 0, stream>>>(nbrS_out, keyS_out, etS_out, cdot_out, rdot_out, gdot_out, ewS_out, E, 2);
    k_gcb<<<((int)(((size_t)M * 128 + 255) / 256)), 256, 0, stream>>>(g, gcomb, M);

    for (int n0 = 0; n0 < N; n0 += C) {
        int rows = (N - n0 < C) ? (N - n0) : C;
        int n1 = n0 + rows;
        int ga = (rows + 3) / 4;
        int gb = (rows + 63) / 64;
        // in-direction (ends=col, nbr=row, self=col)
        k_agg<false><<<ga, 256, 0, stream>>>(offs_in, nbrS_in, etS_in, ewS_in, xn_bf, g_bf, Ac, n0, n1);
        k_mgemm_post<18, 2><<<gb, 256, 0, stream>>>(Ac, Wc_in1, postA, rows, 576);
        // out-direction (ends=row, nbr=col, self=row)
        k_agg<false><<<ga, 256, 0, stream>>>(offs_out, nbrS_out, etS_out, ewS_out, xn_bf, g_bf, Ac, n0, n1);
        k_mgemm_post<18, 2><<<gb, 256, 0, stream>>>(Ac, Wc_out1, postB, rows, 576);
        // fused merge + h1_bf write + hop2 node dots
        k_mergemm<true><<<gb, 256, 0, stream>>>(postA, postB, Wm_i1, Wm_o1, bi1, bo1, Wl1, bl1,
                                                nullptr, h1_bf + (size_t)n0 * 224, wa2_in, wa2_out,
                                                rdot_in + n0, cdot_in + n0, rdot_out + n0, cdot_out + n0,
                                                rows);
    }

    // ---- relation layer: segment sum + fused GEMM (bf16 gp + hop2 gdots) ----
    k_gedges_b<<<M, 384, 0, stream>>>(rsT, csT, offsT, x, invn, g, gcomb, M);
    k_mgemm_rel<<<gM64, 256, 0, stream>>>(gcomb, Wrf_b, brf, gp_bf, wa2_in, wa2_out, gdot_in, gdot_out, M);

    // ---- hop 2 setup (dots already produced by merge/relation epilogues) ----
    k_ew_s<<<(E + 255) / 256, 256, 0, stream>>>(nbrS_in, keyS_in, etS_in, rdot_in, cdot_in, gdot_in, ewS_in, E, 1);
    k_ew_s<<<(E + 255) / 256, 256, 0, stream>>>(nbrS_out, keyS_out, etS_out, cdot_out, rdot_out, gdot_out, ewS_out, E, 1);

    for (int n0 = 0; n0 < N; n0 += C) {
        int rows = (N - n0 < C) ? (N - n0) : C;
        int n1 = n0 + rows;
        int ga = (rows + 3) / 4;
        int gb = (rows + 63) / 64;
        k_agg<true><<<ga, 256, 0, stream>>>(offs_in, nbrS_in, etS_in, ewS_in, h1_bf, gp_bf, Ac, n0, n1);
        k_mgemm_post<21, 1><<<gb, 256, 0, stream>>>(Ac, Wc_in2, postA, rows, 672);
        k_agg<true><<<ga, 256, 0, stream>>>(offs_out, nbrS_out, etS_out, ewS_out, h1_bf, gp_bf, Ac, n0, n1);
        k_mgemm_post<21, 1><<<gb, 256, 0, stream>>>(Ac, Wc_out2, postB, rows, 672);
        k_mergemm<false><<<gb, 256, 0, stream>>>(postA, postB, Wm_i2, Wm_o2, bi2, bo2, Wl2, bl2,
                                                 out + (size_t)n0 * 200, nullptr, nullptr, nullptr,
                                                 nullptr, nullptr, nullptr, nullptr, rows);
        // entity residual: out += l2norm(x) @ W_ent^T
        k_mgemm<4, false, true><<<gb, 256, 0, stream>>>(xn_bf + (size_t)n0 * 112, Wb_ent, nullptr,
                                                        out + (size_t)n0 * 200, rows, 112);
    }
}